// Round 8
// baseline (307.717 us; speedup 1.0000x reference)
//
#include <hip/hip_runtime.h>

// ---------------------------------------------------------------------------
// GNN predictor (fp32 I/O). Round 17 = R2/R11 verified pipeline (285.5us:
// fused 69.2 + node2 58 + phase1/bucketB/prep ~158) with the CHEAP kernels
// fixed instead of the fused one:
//   - k_nodeW replaces k_node2: ONE WAVE PER NODE (8 nodes/wave, 3125
//     blocks = 12 blocks/CU vs old 391 = 1.5/CU). Cross-lane MLP: s[64]
//     coalesced 1 float/lane, layer-1 32 shfl-FMA + shfl_xor(32) combine,
//     layer-2 32 shfl-FMA, coalesced store. Weights in LDS stride 33.
//     58us (grid-starved) -> ~15us predicted.
//   - k_bucketB: cursor-scatter goes to dynamic LDS (C*4=32KB), ssrc then
//     written COALESCED. Scattered 4B HBM writes -> LDS. ~40 -> ~20us.
// R7 LESSON: folding node-MLP into fused costs VGPR 76->124, occupancy
// 28->19%, fused 135us >= split 127us. Keep split; sumh round-trip is ~8us.
// R5 LESSON: epilogue asm "memory" fences block next-node overlap (+61us).
// R12/R13 LESSON (R4): per-edge device-scope atomic scatter = ~64B RMW each
// on non-coherent-L2 MI355X (VALUBusy 7%). Keep LDS-aggregated bucket sort.
// R10 LESSON: global-cursor dynamic chunking regressed 4.5x. Static ranges.
// Fused VALU diet (verified R11): tanh scale folded into W2e/b2e;
// sum tanh = deg - 2*sum sigma; pairwise rcp; full/tail batch split.
// ---------------------------------------------------------------------------

#define LRELU_SLOPE 0.01f
#define BUCK_SHIFT 8                  // 256 nodes per bucket
#define TANH_SCALE 2.8853900817779268f  // 2*log2(e), folded into W2e/b2e
#define NPW_NODE 8                    // nodes per wave in k_nodeW

constexpr int OFF_W1ET  = 0;          // [32][76]  edge W1 transposed
constexpr int OFF_B1E   = 2432;       // [32]
constexpr int OFF_B2E   = 4512;       // [64]      pre-scaled by TANH_SCALE
constexpr int OFF_W1NA  = 4576;       // [32][76]  node W1 (pos,u,h dims) in x76 order
constexpr int OFF_W1NS  = 7008;       // [32][64]  node W1 (sumh dims) transposed
constexpr int OFF_W2N   = 9056;       // [32][64]
constexpr int OFF_B2N   = 11104;      // [64]
constexpr int OFF_B1N   = 11168;      // [32]
constexpr int OFF_W1POS = 11200;      // [32] float2 (W1e rows 2,3)
constexpr int W_TOTAL   = 11264;

typedef __bf16 bf16x8 __attribute__((ext_vector_type(8)));
typedef float  f32x4  __attribute__((ext_vector_type(4)));

__device__ __forceinline__ float ftanh(float x) {
    float e = __builtin_amdgcn_exp2f(x * 2.8853900817779268f);
    return 1.0f - 2.0f * __builtin_amdgcn_rcpf(e + 1.0f);
}
__device__ __forceinline__ unsigned f2bf_pair(float f0, float f1) {
    unsigned u0 = __float_as_uint(f0), u1 = __float_as_uint(f1);
    unsigned r0 = (u0 + 0x7fffu + ((u0 >> 16) & 1u)) >> 16;   // RNE
    unsigned r1 = (u1 + 0x7fffu + ((u1 >> 16) & 1u)) >> 16;
    return r0 | (r1 << 16);
}
__device__ __forceinline__ float bf_lo(unsigned p) { return __uint_as_float(p << 16); }
__device__ __forceinline__ float bf_hi(unsigned p) { return __uint_as_float(p & 0xffff0000u); }

// ---------------------------------------------------------------------------
__global__ void prep_weights(const float* __restrict__ W1e, const float* __restrict__ b1e,
                             const float* __restrict__ W2e, const float* __restrict__ b2e,
                             const float* __restrict__ W1n, const float* __restrict__ b1n,
                             const float* __restrict__ W2n, const float* __restrict__ b2n,
                             float* __restrict__ Wf, uint4* __restrict__ fragW2,
                             int* __restrict__ gcnt, int nbuck) {
    int t = blockIdx.x * blockDim.x + threadIdx.x;
    int T = gridDim.x * blockDim.x;
    for (int idx = t; idx < nbuck; idx += T) gcnt[idx] = 0;
    for (int idx = t; idx < 2432; idx += T) {            // W1e [76][32] -> [32][76]
        int i = idx / 32, j = idx % 32;
        Wf[OFF_W1ET + j * 76 + i] = W1e[idx];
    }
    for (int idx = t; idx < 32; idx += T)   Wf[OFF_B1E + idx] = b1e[idx];
    for (int idx = t; idx < 64; idx += T)   Wf[OFF_B2E + idx] = b2e[idx] * TANH_SCALE;
    // W1NA[j][i]: node-layer1 weights for x76 = [pos(2),0,0,u(8),h(64)]
    for (int idx = t; idx < 2432; idx += T) {
        int j = idx / 76, i = idx % 76;
        float v = 0.f;
        if (i < 2)                 v = W1n[i * 32 + j];
        else if (i >= 4 && i < 12) v = W1n[(130 + (i - 4)) * 32 + j];
        else if (i >= 12)          v = W1n[(2 + (i - 12)) * 32 + j];
        Wf[OFF_W1NA + idx] = v;
    }
    for (int idx = t; idx < 2048; idx += T) {            // W1NS [32][64]
        int j = idx / 64, k = idx % 64;
        Wf[OFF_W1NS + idx] = W1n[(66 + k) * 32 + j];
    }
    for (int idx = t; idx < 2048; idx += T) Wf[OFF_W2N + idx] = W2n[idx];
    for (int idx = t; idx < 64; idx += T)   Wf[OFF_B2N + idx] = b2n[idx];
    for (int idx = t; idx < 32; idx += T)   Wf[OFF_B1N + idx] = b1n[idx];
    for (int idx = t; idx < 32; idx += T) {
        Wf[OFF_W1POS + 2 * idx + 0] = W1e[2 * 32 + idx];
        Wf[OFF_W1POS + 2 * idx + 1] = W1e[3 * 32 + idx];
    }
    // MFMA B-fragments for W2e (bf16, pre-scaled), 4 N-tiles x 64 lanes x 16B
    for (int idx = t; idx < 256; idx += T) {
        int tt = idx >> 6, l = idx & 63;
        int colv = l & 15, quadv = l >> 4;
        uint4 v;
        unsigned pk[4];
#pragma unroll
        for (int pr = 0; pr < 4; pr++) {
            int j0 = quadv * 8 + 2 * pr;
            float f0 = W2e[j0 * 64 + 16 * tt + colv] * TANH_SCALE;
            float f1 = W2e[(j0 + 1) * 64 + 16 * tt + colv] * TANH_SCALE;
            pk[pr] = f2bf_pair(f0, f1);
        }
        v.x = pk[0]; v.y = pk[1]; v.z = pk[2]; v.w = pk[3];
        fragW2[tt * 64 + l] = v;
    }
}

// ---------------------------------------------------------------------------
// Phase 1: bucket-scatter (blocks < nblkA, LDS-aggregated histogram) +
// per-node precompute (rest):
//   Abf[n][32] bf16 : edge-MLP layer1 src part
//   A2 [n][32] f32  : node-MLP layer1 pos/h/u part (+b1n)
// ---------------------------------------------------------------------------
__global__ __launch_bounds__(256) void k_phase1(
    const float* __restrict__ hbuf, const float* __restrict__ ubuf,
    const float* __restrict__ posbuf, const float* __restrict__ Wf,
    uint4* __restrict__ Abf, float* __restrict__ A2,
    const int* __restrict__ src, const int* __restrict__ dst,
    int* __restrict__ gcnt, unsigned* __restrict__ pairbuf,
    int E, int N, int C, int nblkA) {
    __shared__ int cnt[512], base[512];
    int tid = threadIdx.x;
    if ((int)blockIdx.x < nblkA) {
        for (int i = tid; i < 512; i += 256) cnt[i] = 0;
        __syncthreads();
        int e0 = blockIdx.x * 4096;
#pragma unroll
        for (int k = 0; k < 16; k++) {
            int e = e0 + k * 256 + tid;
            if (e < E) atomicAdd(&cnt[dst[e] >> BUCK_SHIFT], 1);
        }
        __syncthreads();
        for (int i = tid; i < 512; i += 256) {
            int c = cnt[i];
            base[i] = (c > 0) ? atomicAdd(&gcnt[i], c) : 0;
            cnt[i] = 0;
        }
        __syncthreads();
#pragma unroll
        for (int k = 0; k < 16; k++) {
            int e = e0 + k * 256 + tid;
            if (e < E) {
                int d = dst[e];
                int b = d >> BUCK_SHIFT;
                int r = base[b] + atomicAdd(&cnt[b], 1);
                if (r < C)
                    pairbuf[(size_t)b * C + r] =
                        (unsigned)src[e] | ((unsigned)(d & 255) << 20);
            }
        }
        return;
    }
    // ---- per-node precompute ----
    int n = (blockIdx.x - nblkA) * 256 + tid;
    if (n >= N) return;
    float x[76];
    float2 pp = ((const float2*)posbuf)[n];
    x[0] = pp.x; x[1] = pp.y; x[2] = 0.f; x[3] = 0.f;
    const float4* u4 = (const float4*)ubuf;
#pragma unroll
    for (int c = 0; c < 2; c++) {
        float4 uu = u4[(size_t)n * 2 + c];
        int b = 4 + 4 * c;
        x[b] = uu.x; x[b + 1] = uu.y; x[b + 2] = uu.z; x[b + 3] = uu.w;
    }
    const float4* h4 = (const float4*)hbuf;
#pragma unroll
    for (int c = 0; c < 16; c++) {
        float4 hh = h4[(size_t)n * 16 + c];
        int b = 12 + 4 * c;
        x[b] = hh.x; x[b + 1] = hh.y; x[b + 2] = hh.z; x[b + 3] = hh.w;
    }
    float ar[32];
#pragma unroll 1
    for (int j = 0; j < 32; j++) {
        const float* w1 = Wf + OFF_W1ET + j * 76;
        float a0 = Wf[OFF_B1E + j], a1 = 0.f, a2 = 0.f, a3 = 0.f;
#pragma unroll
        for (int i = 0; i < 76; i += 4) {
            a0 = fmaf(x[i + 0], w1[i + 0], a0);
            a1 = fmaf(x[i + 1], w1[i + 1], a1);
            a2 = fmaf(x[i + 2], w1[i + 2], a2);
            a3 = fmaf(x[i + 3], w1[i + 3], a3);
        }
        ar[j] = (a0 + a1) + (a2 + a3);
    }
#pragma unroll
    for (int c = 0; c < 4; c++) {
        uint4 v;
        v.x = f2bf_pair(ar[8 * c + 0], ar[8 * c + 1]);
        v.y = f2bf_pair(ar[8 * c + 2], ar[8 * c + 3]);
        v.z = f2bf_pair(ar[8 * c + 4], ar[8 * c + 5]);
        v.w = f2bf_pair(ar[8 * c + 6], ar[8 * c + 7]);
        Abf[(size_t)n * 4 + c] = v;
    }
    // node-MLP layer1 pos/h/u part (x[2],x[3] are zero -> harmless)
#pragma unroll 1
    for (int j = 0; j < 32; j++) {
        const float* w1 = Wf + OFF_W1NA + j * 76;
        float a0 = Wf[OFF_B1N + j], a1 = 0.f, a2 = 0.f, a3 = 0.f;
#pragma unroll
        for (int i = 0; i < 76; i += 4) {
            a0 = fmaf(x[i + 0], w1[i + 0], a0);
            a1 = fmaf(x[i + 1], w1[i + 1], a1);
            a2 = fmaf(x[i + 2], w1[i + 2], a2);
            a3 = fmaf(x[i + 3], w1[i + 3], a3);
        }
        ar[j] = (a0 + a1) + (a2 + a3);
    }
#pragma unroll
    for (int c = 0; c < 8; c++) {
        float4 v; v.x = ar[4 * c]; v.y = ar[4 * c + 1];
        v.z = ar[4 * c + 2]; v.w = ar[4 * c + 3];
        ((float4*)(A2 + (size_t)n * 32))[c] = v;
    }
}

// ---------------------------------------------------------------------------
// Pass B: one block per bucket. LDS deg/scan -> seg; cursor-scatter into
// dynamic LDS; ssrc written COALESCED (scattered HBM 4B writes eliminated).
// ---------------------------------------------------------------------------
extern __shared__ unsigned pls[];
__global__ __launch_bounds__(256) void k_bucketB(
    const unsigned* __restrict__ pairbuf, const int* __restrict__ gcnt,
    int2* __restrict__ seg, int* __restrict__ ssrc, int N, int C) {
    __shared__ int deg[256], scn[256], exc[256], cur[256];
    int b = blockIdx.x, tid = threadIdx.x;
    int cntb = gcnt[b];
    cntb = (cntb < C) ? cntb : C;
    deg[tid] = 0; cur[tid] = 0;
    __syncthreads();
    size_t basep = (size_t)b * C;
    for (int i = tid; i < cntb; i += 256)
        atomicAdd(&deg[pairbuf[basep + i] >> 20], 1);
    __syncthreads();
    scn[tid] = deg[tid];
    __syncthreads();
    for (int st = 1; st < 256; st <<= 1) {
        int add = (tid >= st) ? scn[tid - st] : 0;
        __syncthreads();
        scn[tid] += add;
        __syncthreads();
    }
    int ex = scn[tid] - deg[tid];
    exc[tid] = ex;
    int n = (b << BUCK_SHIFT) + tid;
    if (n < N) {
        int lo = b * C + ex;
        seg[n] = make_int2(lo, lo + deg[tid]);
    }
    __syncthreads();
    // scatter into LDS (pairbuf re-read is L2-hot: same 16KB just read)
    for (int i = tid; i < cntb; i += 256) {
        unsigned p = pairbuf[basep + i];
        int l = (int)(p >> 20);
        int slot = exc[l] + atomicAdd(&cur[l], 1);
        pls[slot] = p & 0xFFFFFu;
    }
    __syncthreads();
    for (int i = tid; i < cntb; i += 256)
        ssrc[basep + i] = (int)pls[i];
}

// ---------------------------------------------------------------------------
// Fused edge-MLP + gather (EXACT R11/R2 verified 69.2us kernel).
// ---------------------------------------------------------------------------
__global__ __launch_bounds__(256) void fused_edge_gather(
    const int2* __restrict__ seg, const int* __restrict__ ssrc,
    const uint4* __restrict__ Abf, const float* __restrict__ posbuf,
    const float* __restrict__ Wf, const uint4* __restrict__ fragW2,
    float* __restrict__ sumh, int N, int npw) {
    int wid = blockIdx.x * 4 + (threadIdx.x >> 6);
    int lane = threadIdx.x & 63;
    int col = lane & 15, quad = lane >> 4;

    union { uint4 u; bf16x8 v; } cvt;
    bf16x8 bfr[4];
#pragma unroll
    for (int t = 0; t < 4; t++) {
        cvt.u = fragW2[t * 64 + lane];
        bfr[t] = cvt.v;
    }
    float c0[4];
#pragma unroll
    for (int t = 0; t < 4; t++) c0[t] = Wf[OFF_B2E + 16 * t + col];
    float wx[8], wy[8];
#pragma unroll
    for (int jj = 0; jj < 8; jj++) {
        float2 wv = ((const float2*)(Wf + OFF_W1POS))[quad * 8 + jj];
        wx[jj] = wv.x; wy[jj] = wv.y;
    }

    int n0 = wid * npw;
    int n1 = n0 + npw; n1 = (n1 < N) ? n1 : N;
#pragma unroll 1
    for (int n = n0; n < n1; n++) {
        int2 sg = seg[n];
        int lo = sg.x, hi = sg.y, deg = hi - lo;
        float2 pd = ((const float2*)posbuf)[n];
        float padd[8];
#pragma unroll
        for (int jj = 0; jj < 8; jj++)
            padd[jj] = fmaf(pd.x, wx[jj], pd.y * wy[jj]);

        float s0[4] = {0.f, 0.f, 0.f, 0.f};
        if (deg > 0) {
            int te = lo + col;
            te = (te < hi) ? te : (hi - 1);
            uint4 ar = Abf[(size_t)ssrc[te] * 4 + quad];
            int nfull = deg & ~15;
#pragma unroll 1
            for (int b = 0; b < nfull; b += 16) {
                // prefetch next batch (clamped; harmless re-read at the end)
                int teN = lo + b + 16 + col;
                teN = (teN < hi) ? teN : (hi - 1);
                uint4 arN = Abf[(size_t)ssrc[teN] * 4 + quad];

                bf16x8 af;
                {
                    float v0 = bf_lo(ar.x) + padd[0], v1 = bf_hi(ar.x) + padd[1];
                    float v2 = bf_lo(ar.y) + padd[2], v3 = bf_hi(ar.y) + padd[3];
                    float v4 = bf_lo(ar.z) + padd[4], v5 = bf_hi(ar.z) + padd[5];
                    float v6 = bf_lo(ar.w) + padd[6], v7 = bf_hi(ar.w) + padd[7];
                    v0 = fmaxf(v0, LRELU_SLOPE * v0); v1 = fmaxf(v1, LRELU_SLOPE * v1);
                    v2 = fmaxf(v2, LRELU_SLOPE * v2); v3 = fmaxf(v3, LRELU_SLOPE * v3);
                    v4 = fmaxf(v4, LRELU_SLOPE * v4); v5 = fmaxf(v5, LRELU_SLOPE * v5);
                    v6 = fmaxf(v6, LRELU_SLOPE * v6); v7 = fmaxf(v7, LRELU_SLOPE * v7);
                    af[0] = (__bf16)v0; af[1] = (__bf16)v1; af[2] = (__bf16)v2; af[3] = (__bf16)v3;
                    af[4] = (__bf16)v4; af[5] = (__bf16)v5; af[6] = (__bf16)v6; af[7] = (__bf16)v7;
                }
#pragma unroll
                for (int t = 0; t < 4; t++) {
                    f32x4 acc = {c0[t], c0[t], c0[t], c0[t]};
                    acc = __builtin_amdgcn_mfma_f32_16x16x32_bf16(af, bfr[t], acc, 0, 0, 0);
                    float u0 = __builtin_amdgcn_exp2f(acc[0]);
                    float u1 = __builtin_amdgcn_exp2f(acc[1]);
                    float u2 = __builtin_amdgcn_exp2f(acc[2]);
                    float u3 = __builtin_amdgcn_exp2f(acc[3]);
                    float q01 = u0 + u1, q23 = u2 + u3;
                    float d01 = fmaf(u0, u1, q01) + 1.f;
                    float d23 = fmaf(u2, u3, q23) + 1.f;
                    s0[t] = fmaf(q01 + 2.f, __builtin_amdgcn_rcpf(d01), s0[t]);
                    s0[t] = fmaf(q23 + 2.f, __builtin_amdgcn_rcpf(d23), s0[t]);
                }
                ar = arN;
            }
            int tail = deg - nfull;
            if (tail) {
                bf16x8 af;
                {
                    float v0 = bf_lo(ar.x) + padd[0], v1 = bf_hi(ar.x) + padd[1];
                    float v2 = bf_lo(ar.y) + padd[2], v3 = bf_hi(ar.y) + padd[3];
                    float v4 = bf_lo(ar.z) + padd[4], v5 = bf_hi(ar.z) + padd[5];
                    float v6 = bf_lo(ar.w) + padd[6], v7 = bf_hi(ar.w) + padd[7];
                    v0 = fmaxf(v0, LRELU_SLOPE * v0); v1 = fmaxf(v1, LRELU_SLOPE * v1);
                    v2 = fmaxf(v2, LRELU_SLOPE * v2); v3 = fmaxf(v3, LRELU_SLOPE * v3);
                    v4 = fmaxf(v4, LRELU_SLOPE * v4); v5 = fmaxf(v5, LRELU_SLOPE * v5);
                    v6 = fmaxf(v6, LRELU_SLOPE * v6); v7 = fmaxf(v7, LRELU_SLOPE * v7);
                    af[0] = (__bf16)v0; af[1] = (__bf16)v1; af[2] = (__bf16)v2; af[3] = (__bf16)v3;
                    af[4] = (__bf16)v4; af[5] = (__bf16)v5; af[6] = (__bf16)v6; af[7] = (__bf16)v7;
                }
                int rowb = quad * 4;
#pragma unroll
                for (int t = 0; t < 4; t++) {
                    f32x4 acc = {c0[t], c0[t], c0[t], c0[t]};
                    acc = __builtin_amdgcn_mfma_f32_16x16x32_bf16(af, bfr[t], acc, 0, 0, 0);
                    // invalid rows: u = 1e30 -> pair algebra makes the
                    // contribution ~2^-60 (drops out); double-invalid ~0.
                    float u0 = (rowb + 0 < tail) ? __builtin_amdgcn_exp2f(acc[0]) : 1e30f;
                    float u1 = (rowb + 1 < tail) ? __builtin_amdgcn_exp2f(acc[1]) : 1e30f;
                    float u2 = (rowb + 2 < tail) ? __builtin_amdgcn_exp2f(acc[2]) : 1e30f;
                    float u3 = (rowb + 3 < tail) ? __builtin_amdgcn_exp2f(acc[3]) : 1e30f;
                    float q01 = u0 + u1, q23 = u2 + u3;
                    float d01 = fmaf(u0, u1, q01) + 1.f;
                    float d23 = fmaf(u2, u3, q23) + 1.f;
                    s0[t] = fmaf(q01 + 2.f, __builtin_amdgcn_rcpf(d01), s0[t]);
                    s0[t] = fmaf(q23 + 2.f, __builtin_amdgcn_rcpf(d23), s0[t]);
                }
            }
        }
#pragma unroll
        for (int t = 0; t < 4; t++) {
            s0[t] += __shfl_xor(s0[t], 16);
            s0[t] += __shfl_xor(s0[t], 32);
        }
        if (lane < 16) {
            float* sr = sumh + (size_t)n * 64;
            float fd = (float)deg;
#pragma unroll
            for (int t = 0; t < 4; t++) sr[16 * t + lane] = fmaf(-2.f, s0[t], fd);
        }
    }
}

// ---------------------------------------------------------------------------
// Node MLP, one wave per node (NPW_NODE nodes per wave). Cross-lane only:
// layer-1 lane=(j=lane&31, half=lane>>5) does 32 shfl-FMA over its half of
// s; halves combined by shfl_xor(32); layer-2 lane=k does 32 shfl-FMA over
// y[j]. Weights in LDS stride 33 (2 lanes/bank = free). All loads/stores
// coalesced.
// ---------------------------------------------------------------------------
__global__ __launch_bounds__(256) void k_nodeW(
    const float* __restrict__ A2, const float* __restrict__ sumh,
    const float* __restrict__ Wf, float* __restrict__ out, int N) {
    __shared__ float w1L[64 * 33];   // [lane][i']: W1NS[lane&31][(lane>>5)*32+i']
    __shared__ float w2L[64 * 33];   // [lane][j] : W2n[j][lane]

    int wv = threadIdx.x >> 6;
    int lane = threadIdx.x & 63;

    for (int idx = threadIdx.x; idx < 2048; idx += 256) {
        int l = idx >> 5, i = idx & 31;
        w1L[l * 33 + i] = Wf[OFF_W1NS + (l & 31) * 64 + (l >> 5) * 32 + i];
        w2L[l * 33 + i] = Wf[OFF_W2N + i * 64 + l];
    }
    float b2nk = Wf[OFF_B2N + lane];
    __syncthreads();

    const float* w1r = w1L + lane * 33;
    const float* w2r = w2L + lane * 33;
    int bbase = lane & 32;

    int w = blockIdx.x * 4 + wv;
    int n0 = w * NPW_NODE;
    int n1 = n0 + NPW_NODE; n1 = (n1 < N) ? n1 : N;
#pragma unroll 1
    for (int n = n0; n < n1; n++) {
        float sval = sumh[(size_t)n * 64 + lane];
        float a0 = (lane < 32) ? A2[(size_t)n * 32 + lane] : 0.f;
        float a1 = 0.f, a2 = 0.f, a3 = 0.f;
#pragma unroll
        for (int ic = 0; ic < 32; ic += 4) {
            float sv0 = __shfl(sval, bbase | ic);
            float sv1 = __shfl(sval, bbase | (ic + 1));
            float sv2 = __shfl(sval, bbase | (ic + 2));
            float sv3 = __shfl(sval, bbase | (ic + 3));
            a0 = fmaf(sv0, w1r[ic + 0], a0);
            a1 = fmaf(sv1, w1r[ic + 1], a1);
            a2 = fmaf(sv2, w1r[ic + 2], a2);
            a3 = fmaf(sv3, w1r[ic + 3], a3);
        }
        float part = (a0 + a1) + (a2 + a3);
        float yo = part + __shfl_xor(part, 32);
        yo = fmaxf(yo, LRELU_SLOPE * yo);

        float ok0 = b2nk, ok1 = 0.f;
#pragma unroll
        for (int j = 0; j < 32; j += 2) {
            float yj0 = __shfl(yo, j);
            float yj1 = __shfl(yo, j + 1);
            ok0 = fmaf(yj0, w2r[j], ok0);
            ok1 = fmaf(yj1, w2r[j + 1], ok1);
        }
        out[(size_t)n * 64 + lane] = ftanh(ok0 + ok1);
    }
}

// ---------------------------------------------------------------------------
extern "C" void kernel_launch(void* const* d_in, const int* in_sizes, int n_in,
                              void* d_out, int out_size, void* d_ws, size_t ws_size,
                              hipStream_t stream) {
    const float* hbuf   = (const float*)d_in[0];
    const float* ubuf   = (const float*)d_in[1];
    const float* posbuf = (const float*)d_in[2];
    const int* src = (const int*)d_in[3];
    const int* dst = (const int*)d_in[4];

    int N = in_sizes[0] / 64;
    int E = in_sizes[3];
    int NBUCK = (N + 255) >> BUCK_SHIFT;                 // 256-node buckets
    int C = ((2 * ((E + NBUCK - 1) / NBUCK)) + 255) & ~255;  // bucket capacity
    int nblkA = (E + 4095) / 4096;

    char* p = (char*)d_ws;
    auto alloc = [&](size_t bytes) {
        char* r = p;
        p += (bytes + 255) & ~(size_t)255;
        return r;
    };
    float*    Wf      = (float*)alloc(W_TOTAL * 4);
    uint4*    fragW2  = (uint4*)alloc(4 * 64 * 16);
    uint4*    Abf     = (uint4*)alloc((size_t)N * 64);   // bf16 A rows, 64B
    float*    A2      = (float*)alloc((size_t)N * 32 * 4);
    float*    sumh    = (float*)alloc((size_t)N * 64 * 4);
    int2*     seg     = (int2*)alloc((size_t)N * 8);
    int*      gcnt    = (int*)alloc((size_t)NBUCK * 4);
    unsigned* pairbuf = (unsigned*)alloc((size_t)NBUCK * C * 4);
    int*      ssrc    = (int*)alloc((size_t)NBUCK * C * 4);

    prep_weights<<<32, 256, 0, stream>>>(
        (const float*)d_in[5], (const float*)d_in[6],
        (const float*)d_in[7], (const float*)d_in[8],
        (const float*)d_in[9], (const float*)d_in[10],
        (const float*)d_in[11], (const float*)d_in[12], Wf, fragW2,
        gcnt, NBUCK);

    int nblkP = nblkA + (N + 255) / 256;
    k_phase1<<<nblkP, 256, 0, stream>>>(
        hbuf, ubuf, posbuf, Wf, Abf, A2, src, dst, gcnt, pairbuf, E, N, C, nblkA);

    k_bucketB<<<NBUCK, 256, (size_t)C * 4, stream>>>(
        pairbuf, gcnt, seg, ssrc, N, C);

    const int FBLK = 2048;                    // 8192 waves = full machine
    int npw = (N + FBLK * 4 - 1) / (FBLK * 4);
    fused_edge_gather<<<FBLK, 256, 0, stream>>>(
        seg, ssrc, Abf, posbuf, Wf, fragW2, sumh, N, npw);

    int nodeBlocks = (N + 4 * NPW_NODE - 1) / (4 * NPW_NODE);
    k_nodeW<<<nodeBlocks, 256, 0, stream>>>(
        A2, sumh, Wf, (float*)d_out, N);
}

// Round 9
// 299.950 us; speedup vs baseline: 1.0259x; 1.0259x over previous
//
#include <hip/hip_runtime.h>

// ---------------------------------------------------------------------------
// GNN predictor (fp32 I/O). Round 18 = R8 pipeline with k_nodeW replaced by
// k_node3: 2 threads/node, WAVE-level split (wave half h: layer-1 j in
// [16h,16h+16), layer-2 k in [32h,32h+32)) so weights stay WAVE-UNIFORM ->
// SGPR operands via scalar pipe (v_fmac v,s,v), zero LDS weight traffic.
// y exchanged via LDS [128][33] (rotating banks) + one barrier. 3128 waves
// (2x k_node2), ~2048 FMA/thread.
// R8 LESSON (measured): k_nodeW's __shfl broadcasts + per-lane LDS weight
// reads = ~128 LDS-pipe ops/node (ds_bpermute IS an LDS op) -> LDS-pipe
// bound: 88us, VALUBusy 20%. Weights must ride the SCALAR pipe (uniform
// s_load), broadcasts minimized.
// R7 LESSON: folding node-MLP into fused costs VGPR 76->124, occ 19%. Split.
// R12/R13 LESSON (R4): per-edge device-scope atomic scatter = ~64B RMW each.
// Keep LDS-aggregated bucket sort.
// R10 LESSON: global-cursor dynamic chunking regressed 4.5x. Static ranges.
// Fused VALU diet (verified R11): tanh scale folded into W2e/b2e;
// sum tanh = deg - 2*sum sigma; pairwise rcp; full/tail batch split.
// ---------------------------------------------------------------------------

#define LRELU_SLOPE 0.01f
#define BUCK_SHIFT 8                  // 256 nodes per bucket
#define TANH_SCALE 2.8853900817779268f  // 2*log2(e), folded into W2e/b2e

constexpr int OFF_W1ET  = 0;          // [32][76]  edge W1 transposed
constexpr int OFF_B1E   = 2432;       // [32]
constexpr int OFF_B2E   = 4512;       // [64]      pre-scaled by TANH_SCALE
constexpr int OFF_W1NA  = 4576;       // [32][76]  node W1 (pos,u,h dims) in x76 order
constexpr int OFF_W1NS  = 7008;       // [32][64]  node W1 (sumh dims) transposed
constexpr int OFF_W2N   = 9056;       // [32][64]
constexpr int OFF_B2N   = 11104;      // [64]
constexpr int OFF_B1N   = 11168;      // [32]
constexpr int OFF_W1POS = 11200;      // [32] float2 (W1e rows 2,3)
constexpr int W_TOTAL   = 11264;

typedef __bf16 bf16x8 __attribute__((ext_vector_type(8)));
typedef float  f32x4  __attribute__((ext_vector_type(4)));

__device__ __forceinline__ float ftanh(float x) {
    float e = __builtin_amdgcn_exp2f(x * 2.8853900817779268f);
    return 1.0f - 2.0f * __builtin_amdgcn_rcpf(e + 1.0f);
}
__device__ __forceinline__ unsigned f2bf_pair(float f0, float f1) {
    unsigned u0 = __float_as_uint(f0), u1 = __float_as_uint(f1);
    unsigned r0 = (u0 + 0x7fffu + ((u0 >> 16) & 1u)) >> 16;   // RNE
    unsigned r1 = (u1 + 0x7fffu + ((u1 >> 16) & 1u)) >> 16;
    return r0 | (r1 << 16);
}
__device__ __forceinline__ float bf_lo(unsigned p) { return __uint_as_float(p << 16); }
__device__ __forceinline__ float bf_hi(unsigned p) { return __uint_as_float(p & 0xffff0000u); }

// ---------------------------------------------------------------------------
__global__ void prep_weights(const float* __restrict__ W1e, const float* __restrict__ b1e,
                             const float* __restrict__ W2e, const float* __restrict__ b2e,
                             const float* __restrict__ W1n, const float* __restrict__ b1n,
                             const float* __restrict__ W2n, const float* __restrict__ b2n,
                             float* __restrict__ Wf, uint4* __restrict__ fragW2,
                             int* __restrict__ gcnt, int nbuck) {
    int t = blockIdx.x * blockDim.x + threadIdx.x;
    int T = gridDim.x * blockDim.x;
    for (int idx = t; idx < nbuck; idx += T) gcnt[idx] = 0;
    for (int idx = t; idx < 2432; idx += T) {            // W1e [76][32] -> [32][76]
        int i = idx / 32, j = idx % 32;
        Wf[OFF_W1ET + j * 76 + i] = W1e[idx];
    }
    for (int idx = t; idx < 32; idx += T)   Wf[OFF_B1E + idx] = b1e[idx];
    for (int idx = t; idx < 64; idx += T)   Wf[OFF_B2E + idx] = b2e[idx] * TANH_SCALE;
    // W1NA[j][i]: node-layer1 weights for x76 = [pos(2),0,0,u(8),h(64)]
    for (int idx = t; idx < 2432; idx += T) {
        int j = idx / 76, i = idx % 76;
        float v = 0.f;
        if (i < 2)                 v = W1n[i * 32 + j];
        else if (i >= 4 && i < 12) v = W1n[(130 + (i - 4)) * 32 + j];
        else if (i >= 12)          v = W1n[(2 + (i - 12)) * 32 + j];
        Wf[OFF_W1NA + idx] = v;
    }
    for (int idx = t; idx < 2048; idx += T) {            // W1NS [32][64]
        int j = idx / 64, k = idx % 64;
        Wf[OFF_W1NS + idx] = W1n[(66 + k) * 32 + j];
    }
    for (int idx = t; idx < 2048; idx += T) Wf[OFF_W2N + idx] = W2n[idx];
    for (int idx = t; idx < 64; idx += T)   Wf[OFF_B2N + idx] = b2n[idx];
    for (int idx = t; idx < 32; idx += T)   Wf[OFF_B1N + idx] = b1n[idx];
    for (int idx = t; idx < 32; idx += T) {
        Wf[OFF_W1POS + 2 * idx + 0] = W1e[2 * 32 + idx];
        Wf[OFF_W1POS + 2 * idx + 1] = W1e[3 * 32 + idx];
    }
    // MFMA B-fragments for W2e (bf16, pre-scaled), 4 N-tiles x 64 lanes x 16B
    for (int idx = t; idx < 256; idx += T) {
        int tt = idx >> 6, l = idx & 63;
        int colv = l & 15, quadv = l >> 4;
        uint4 v;
        unsigned pk[4];
#pragma unroll
        for (int pr = 0; pr < 4; pr++) {
            int j0 = quadv * 8 + 2 * pr;
            float f0 = W2e[j0 * 64 + 16 * tt + colv] * TANH_SCALE;
            float f1 = W2e[(j0 + 1) * 64 + 16 * tt + colv] * TANH_SCALE;
            pk[pr] = f2bf_pair(f0, f1);
        }
        v.x = pk[0]; v.y = pk[1]; v.z = pk[2]; v.w = pk[3];
        fragW2[tt * 64 + l] = v;
    }
}

// ---------------------------------------------------------------------------
// Phase 1: bucket-scatter (blocks < nblkA, LDS-aggregated histogram) +
// per-node precompute (rest):
//   Abf[n][32] bf16 : edge-MLP layer1 src part
//   A2 [n][32] f32  : node-MLP layer1 pos/h/u part (+b1n)
// ---------------------------------------------------------------------------
__global__ __launch_bounds__(256) void k_phase1(
    const float* __restrict__ hbuf, const float* __restrict__ ubuf,
    const float* __restrict__ posbuf, const float* __restrict__ Wf,
    uint4* __restrict__ Abf, float* __restrict__ A2,
    const int* __restrict__ src, const int* __restrict__ dst,
    int* __restrict__ gcnt, unsigned* __restrict__ pairbuf,
    int E, int N, int C, int nblkA) {
    __shared__ int cnt[512], base[512];
    int tid = threadIdx.x;
    if ((int)blockIdx.x < nblkA) {
        for (int i = tid; i < 512; i += 256) cnt[i] = 0;
        __syncthreads();
        int e0 = blockIdx.x * 4096;
#pragma unroll
        for (int k = 0; k < 16; k++) {
            int e = e0 + k * 256 + tid;
            if (e < E) atomicAdd(&cnt[dst[e] >> BUCK_SHIFT], 1);
        }
        __syncthreads();
        for (int i = tid; i < 512; i += 256) {
            int c = cnt[i];
            base[i] = (c > 0) ? atomicAdd(&gcnt[i], c) : 0;
            cnt[i] = 0;
        }
        __syncthreads();
#pragma unroll
        for (int k = 0; k < 16; k++) {
            int e = e0 + k * 256 + tid;
            if (e < E) {
                int d = dst[e];
                int b = d >> BUCK_SHIFT;
                int r = base[b] + atomicAdd(&cnt[b], 1);
                if (r < C)
                    pairbuf[(size_t)b * C + r] =
                        (unsigned)src[e] | ((unsigned)(d & 255) << 20);
            }
        }
        return;
    }
    // ---- per-node precompute ----
    int n = (blockIdx.x - nblkA) * 256 + tid;
    if (n >= N) return;
    float x[76];
    float2 pp = ((const float2*)posbuf)[n];
    x[0] = pp.x; x[1] = pp.y; x[2] = 0.f; x[3] = 0.f;
    const float4* u4 = (const float4*)ubuf;
#pragma unroll
    for (int c = 0; c < 2; c++) {
        float4 uu = u4[(size_t)n * 2 + c];
        int b = 4 + 4 * c;
        x[b] = uu.x; x[b + 1] = uu.y; x[b + 2] = uu.z; x[b + 3] = uu.w;
    }
    const float4* h4 = (const float4*)hbuf;
#pragma unroll
    for (int c = 0; c < 16; c++) {
        float4 hh = h4[(size_t)n * 16 + c];
        int b = 12 + 4 * c;
        x[b] = hh.x; x[b + 1] = hh.y; x[b + 2] = hh.z; x[b + 3] = hh.w;
    }
    float ar[32];
#pragma unroll 1
    for (int j = 0; j < 32; j++) {
        const float* w1 = Wf + OFF_W1ET + j * 76;
        float a0 = Wf[OFF_B1E + j], a1 = 0.f, a2 = 0.f, a3 = 0.f;
#pragma unroll
        for (int i = 0; i < 76; i += 4) {
            a0 = fmaf(x[i + 0], w1[i + 0], a0);
            a1 = fmaf(x[i + 1], w1[i + 1], a1);
            a2 = fmaf(x[i + 2], w1[i + 2], a2);
            a3 = fmaf(x[i + 3], w1[i + 3], a3);
        }
        ar[j] = (a0 + a1) + (a2 + a3);
    }
#pragma unroll
    for (int c = 0; c < 4; c++) {
        uint4 v;
        v.x = f2bf_pair(ar[8 * c + 0], ar[8 * c + 1]);
        v.y = f2bf_pair(ar[8 * c + 2], ar[8 * c + 3]);
        v.z = f2bf_pair(ar[8 * c + 4], ar[8 * c + 5]);
        v.w = f2bf_pair(ar[8 * c + 6], ar[8 * c + 7]);
        Abf[(size_t)n * 4 + c] = v;
    }
    // node-MLP layer1 pos/h/u part (x[2],x[3] are zero -> harmless)
#pragma unroll 1
    for (int j = 0; j < 32; j++) {
        const float* w1 = Wf + OFF_W1NA + j * 76;
        float a0 = Wf[OFF_B1N + j], a1 = 0.f, a2 = 0.f, a3 = 0.f;
#pragma unroll
        for (int i = 0; i < 76; i += 4) {
            a0 = fmaf(x[i + 0], w1[i + 0], a0);
            a1 = fmaf(x[i + 1], w1[i + 1], a1);
            a2 = fmaf(x[i + 2], w1[i + 2], a2);
            a3 = fmaf(x[i + 3], w1[i + 3], a3);
        }
        ar[j] = (a0 + a1) + (a2 + a3);
    }
#pragma unroll
    for (int c = 0; c < 8; c++) {
        float4 v; v.x = ar[4 * c]; v.y = ar[4 * c + 1];
        v.z = ar[4 * c + 2]; v.w = ar[4 * c + 3];
        ((float4*)(A2 + (size_t)n * 32))[c] = v;
    }
}

// ---------------------------------------------------------------------------
// Pass B: one block per bucket. LDS deg/scan -> seg; cursor-scatter into
// dynamic LDS; ssrc written COALESCED.
// ---------------------------------------------------------------------------
extern __shared__ unsigned pls[];
__global__ __launch_bounds__(256) void k_bucketB(
    const unsigned* __restrict__ pairbuf, const int* __restrict__ gcnt,
    int2* __restrict__ seg, int* __restrict__ ssrc, int N, int C) {
    __shared__ int deg[256], scn[256], exc[256], cur[256];
    int b = blockIdx.x, tid = threadIdx.x;
    int cntb = gcnt[b];
    cntb = (cntb < C) ? cntb : C;
    deg[tid] = 0; cur[tid] = 0;
    __syncthreads();
    size_t basep = (size_t)b * C;
    for (int i = tid; i < cntb; i += 256)
        atomicAdd(&deg[pairbuf[basep + i] >> 20], 1);
    __syncthreads();
    scn[tid] = deg[tid];
    __syncthreads();
    for (int st = 1; st < 256; st <<= 1) {
        int add = (tid >= st) ? scn[tid - st] : 0;
        __syncthreads();
        scn[tid] += add;
        __syncthreads();
    }
    int ex = scn[tid] - deg[tid];
    exc[tid] = ex;
    int n = (b << BUCK_SHIFT) + tid;
    if (n < N) {
        int lo = b * C + ex;
        seg[n] = make_int2(lo, lo + deg[tid]);
    }
    __syncthreads();
    // scatter into LDS (pairbuf re-read is L2-hot)
    for (int i = tid; i < cntb; i += 256) {
        unsigned p = pairbuf[basep + i];
        int l = (int)(p >> 20);
        int slot = exc[l] + atomicAdd(&cur[l], 1);
        pls[slot] = p & 0xFFFFFu;
    }
    __syncthreads();
    for (int i = tid; i < cntb; i += 256)
        ssrc[basep + i] = (int)pls[i];
}

// ---------------------------------------------------------------------------
// Fused edge-MLP + gather (EXACT R11/R2 verified 69.2us kernel).
// ---------------------------------------------------------------------------
__global__ __launch_bounds__(256) void fused_edge_gather(
    const int2* __restrict__ seg, const int* __restrict__ ssrc,
    const uint4* __restrict__ Abf, const float* __restrict__ posbuf,
    const float* __restrict__ Wf, const uint4* __restrict__ fragW2,
    float* __restrict__ sumh, int N, int npw) {
    int wid = blockIdx.x * 4 + (threadIdx.x >> 6);
    int lane = threadIdx.x & 63;
    int col = lane & 15, quad = lane >> 4;

    union { uint4 u; bf16x8 v; } cvt;
    bf16x8 bfr[4];
#pragma unroll
    for (int t = 0; t < 4; t++) {
        cvt.u = fragW2[t * 64 + lane];
        bfr[t] = cvt.v;
    }
    float c0[4];
#pragma unroll
    for (int t = 0; t < 4; t++) c0[t] = Wf[OFF_B2E + 16 * t + col];
    float wx[8], wy[8];
#pragma unroll
    for (int jj = 0; jj < 8; jj++) {
        float2 wv = ((const float2*)(Wf + OFF_W1POS))[quad * 8 + jj];
        wx[jj] = wv.x; wy[jj] = wv.y;
    }

    int n0 = wid * npw;
    int n1 = n0 + npw; n1 = (n1 < N) ? n1 : N;
#pragma unroll 1
    for (int n = n0; n < n1; n++) {
        int2 sg = seg[n];
        int lo = sg.x, hi = sg.y, deg = hi - lo;
        float2 pd = ((const float2*)posbuf)[n];
        float padd[8];
#pragma unroll
        for (int jj = 0; jj < 8; jj++)
            padd[jj] = fmaf(pd.x, wx[jj], pd.y * wy[jj]);

        float s0[4] = {0.f, 0.f, 0.f, 0.f};
        if (deg > 0) {
            int te = lo + col;
            te = (te < hi) ? te : (hi - 1);
            uint4 ar = Abf[(size_t)ssrc[te] * 4 + quad];
            int nfull = deg & ~15;
#pragma unroll 1
            for (int b = 0; b < nfull; b += 16) {
                // prefetch next batch (clamped; harmless re-read at the end)
                int teN = lo + b + 16 + col;
                teN = (teN < hi) ? teN : (hi - 1);
                uint4 arN = Abf[(size_t)ssrc[teN] * 4 + quad];

                bf16x8 af;
                {
                    float v0 = bf_lo(ar.x) + padd[0], v1 = bf_hi(ar.x) + padd[1];
                    float v2 = bf_lo(ar.y) + padd[2], v3 = bf_hi(ar.y) + padd[3];
                    float v4 = bf_lo(ar.z) + padd[4], v5 = bf_hi(ar.z) + padd[5];
                    float v6 = bf_lo(ar.w) + padd[6], v7 = bf_hi(ar.w) + padd[7];
                    v0 = fmaxf(v0, LRELU_SLOPE * v0); v1 = fmaxf(v1, LRELU_SLOPE * v1);
                    v2 = fmaxf(v2, LRELU_SLOPE * v2); v3 = fmaxf(v3, LRELU_SLOPE * v3);
                    v4 = fmaxf(v4, LRELU_SLOPE * v4); v5 = fmaxf(v5, LRELU_SLOPE * v5);
                    v6 = fmaxf(v6, LRELU_SLOPE * v6); v7 = fmaxf(v7, LRELU_SLOPE * v7);
                    af[0] = (__bf16)v0; af[1] = (__bf16)v1; af[2] = (__bf16)v2; af[3] = (__bf16)v3;
                    af[4] = (__bf16)v4; af[5] = (__bf16)v5; af[6] = (__bf16)v6; af[7] = (__bf16)v7;
                }
#pragma unroll
                for (int t = 0; t < 4; t++) {
                    f32x4 acc = {c0[t], c0[t], c0[t], c0[t]};
                    acc = __builtin_amdgcn_mfma_f32_16x16x32_bf16(af, bfr[t], acc, 0, 0, 0);
                    float u0 = __builtin_amdgcn_exp2f(acc[0]);
                    float u1 = __builtin_amdgcn_exp2f(acc[1]);
                    float u2 = __builtin_amdgcn_exp2f(acc[2]);
                    float u3 = __builtin_amdgcn_exp2f(acc[3]);
                    float q01 = u0 + u1, q23 = u2 + u3;
                    float d01 = fmaf(u0, u1, q01) + 1.f;
                    float d23 = fmaf(u2, u3, q23) + 1.f;
                    s0[t] = fmaf(q01 + 2.f, __builtin_amdgcn_rcpf(d01), s0[t]);
                    s0[t] = fmaf(q23 + 2.f, __builtin_amdgcn_rcpf(d23), s0[t]);
                }
                ar = arN;
            }
            int tail = deg - nfull;
            if (tail) {
                bf16x8 af;
                {
                    float v0 = bf_lo(ar.x) + padd[0], v1 = bf_hi(ar.x) + padd[1];
                    float v2 = bf_lo(ar.y) + padd[2], v3 = bf_hi(ar.y) + padd[3];
                    float v4 = bf_lo(ar.z) + padd[4], v5 = bf_hi(ar.z) + padd[5];
                    float v6 = bf_lo(ar.w) + padd[6], v7 = bf_hi(ar.w) + padd[7];
                    v0 = fmaxf(v0, LRELU_SLOPE * v0); v1 = fmaxf(v1, LRELU_SLOPE * v1);
                    v2 = fmaxf(v2, LRELU_SLOPE * v2); v3 = fmaxf(v3, LRELU_SLOPE * v3);
                    v4 = fmaxf(v4, LRELU_SLOPE * v4); v5 = fmaxf(v5, LRELU_SLOPE * v5);
                    v6 = fmaxf(v6, LRELU_SLOPE * v6); v7 = fmaxf(v7, LRELU_SLOPE * v7);
                    af[0] = (__bf16)v0; af[1] = (__bf16)v1; af[2] = (__bf16)v2; af[3] = (__bf16)v3;
                    af[4] = (__bf16)v4; af[5] = (__bf16)v5; af[6] = (__bf16)v6; af[7] = (__bf16)v7;
                }
                int rowb = quad * 4;
#pragma unroll
                for (int t = 0; t < 4; t++) {
                    f32x4 acc = {c0[t], c0[t], c0[t], c0[t]};
                    acc = __builtin_amdgcn_mfma_f32_16x16x32_bf16(af, bfr[t], acc, 0, 0, 0);
                    // invalid rows: u = 1e30 -> pair algebra makes the
                    // contribution ~2^-60 (drops out); double-invalid ~0.
                    float u0 = (rowb + 0 < tail) ? __builtin_amdgcn_exp2f(acc[0]) : 1e30f;
                    float u1 = (rowb + 1 < tail) ? __builtin_amdgcn_exp2f(acc[1]) : 1e30f;
                    float u2 = (rowb + 2 < tail) ? __builtin_amdgcn_exp2f(acc[2]) : 1e30f;
                    float u3 = (rowb + 3 < tail) ? __builtin_amdgcn_exp2f(acc[3]) : 1e30f;
                    float q01 = u0 + u1, q23 = u2 + u3;
                    float d01 = fmaf(u0, u1, q01) + 1.f;
                    float d23 = fmaf(u2, u3, q23) + 1.f;
                    s0[t] = fmaf(q01 + 2.f, __builtin_amdgcn_rcpf(d01), s0[t]);
                    s0[t] = fmaf(q23 + 2.f, __builtin_amdgcn_rcpf(d23), s0[t]);
                }
            }
        }
#pragma unroll
        for (int t = 0; t < 4; t++) {
            s0[t] += __shfl_xor(s0[t], 16);
            s0[t] += __shfl_xor(s0[t], 32);
        }
        if (lane < 16) {
            float* sr = sumh + (size_t)n * 64;
            float fd = (float)deg;
#pragma unroll
            for (int t = 0; t < 4; t++) sr[16 * t + lane] = fmaf(-2.f, s0[t], fd);
        }
    }
}

// ---------------------------------------------------------------------------
// Node MLP, 2 threads/node, wave-level split. Block = 4 waves = 128 nodes.
// half = wave>>1: layer-1 computes j in [16h,16h+16), layer-2 k in
// [32h,32h+32). Weights wave-uniform -> SGPR (scalar pipe). y exchanged
// via LDS [128][33] (rotating banks, conflict-free), one barrier.
// ---------------------------------------------------------------------------
__global__ __launch_bounds__(256) void k_node3(
    const float* __restrict__ A2, const float* __restrict__ sumh,
    const float* __restrict__ Wf, float* __restrict__ out, int N) {
    __shared__ float ylds[128 * 33];
    int w = threadIdx.x >> 6;        // wave 0..3
    int lane = threadIdx.x & 63;
    int ndl = (w & 1) * 64 + lane;   // node-in-block 0..127
    int half = w >> 1;               // work half
    int n = blockIdx.x * 128 + ndl;
    bool valid = (n < N);

    // ---- layer 1: y[j], j in [16*half, 16*half+16) ----
    float acc[16];
    float4 s4[16];
    if (valid) {
        const float4* sp = (const float4*)(sumh + (size_t)n * 64);
#pragma unroll
        for (int c = 0; c < 16; c++) s4[c] = sp[c];
        const float4* a2p = (const float4*)(A2 + (size_t)n * 32 + half * 16);
#pragma unroll
        for (int jj = 0; jj < 4; jj++) {
            float4 av = a2p[jj];
            acc[4 * jj + 0] = av.x; acc[4 * jj + 1] = av.y;
            acc[4 * jj + 2] = av.z; acc[4 * jj + 3] = av.w;
        }
    } else {
#pragma unroll
        for (int c = 0; c < 16; c++) { s4[c].x = 0.f; s4[c].y = 0.f; s4[c].z = 0.f; s4[c].w = 0.f; }
#pragma unroll
        for (int jj = 0; jj < 16; jj++) acc[jj] = 0.f;
    }
#pragma unroll 1
    for (int jo = 0; jo < 16; jo += 4) {
#pragma unroll
        for (int q = 0; q < 4; q++) {
            int jj = jo + q;
            const float* wrow = Wf + OFF_W1NS + (half * 16 + jj) * 64;  // uniform -> s_load
            float a = acc[jj];
#pragma unroll
            for (int c = 0; c < 16; c++) {
                float4 wv = ((const float4*)wrow)[c];
                a = fmaf(s4[c].x, wv.x, a);
                a = fmaf(s4[c].y, wv.y, a);
                a = fmaf(s4[c].z, wv.z, a);
                a = fmaf(s4[c].w, wv.w, a);
            }
            acc[jj] = fmaxf(a, LRELU_SLOPE * a);
        }
    }
    {
        float* yp = ylds + ndl * 33 + half * 16;
#pragma unroll
        for (int jj = 0; jj < 16; jj++) yp[jj] = acc[jj];
    }
    __syncthreads();

    // ---- layer 2: o[k], k in [32*half, 32*half+32) ----
    float yv[32];
    {
        const float* yp = ylds + ndl * 33;
#pragma unroll
        for (int j = 0; j < 32; j++) yv[j] = yp[j];
    }
    float o[32];
#pragma unroll
    for (int kk = 0; kk < 32; kk++) o[kk] = Wf[OFF_B2N + half * 32 + kk];
#pragma unroll 1
    for (int jo = 0; jo < 32; jo += 4) {
#pragma unroll
        for (int q = 0; q < 4; q++) {
            int j = jo + q;
            const float* w2row = Wf + OFF_W2N + j * 64 + half * 32;     // uniform -> s_load
            float yj = yv[j];
#pragma unroll
            for (int c = 0; c < 8; c++) {
                float4 wv = ((const float4*)w2row)[c];
                o[4 * c + 0] = fmaf(yj, wv.x, o[4 * c + 0]);
                o[4 * c + 1] = fmaf(yj, wv.y, o[4 * c + 1]);
                o[4 * c + 2] = fmaf(yj, wv.z, o[4 * c + 2]);
                o[4 * c + 3] = fmaf(yj, wv.w, o[4 * c + 3]);
            }
        }
    }
    if (valid) {
        float4* op = (float4*)(out + (size_t)n * 64 + half * 32);
#pragma unroll
        for (int c = 0; c < 8; c++) {
            float4 v;
            v.x = ftanh(o[4 * c + 0]); v.y = ftanh(o[4 * c + 1]);
            v.z = ftanh(o[4 * c + 2]); v.w = ftanh(o[4 * c + 3]);
            op[c] = v;
        }
    }
}

// ---------------------------------------------------------------------------
extern "C" void kernel_launch(void* const* d_in, const int* in_sizes, int n_in,
                              void* d_out, int out_size, void* d_ws, size_t ws_size,
                              hipStream_t stream) {
    const float* hbuf   = (const float*)d_in[0];
    const float* ubuf   = (const float*)d_in[1];
    const float* posbuf = (const float*)d_in[2];
    const int* src = (const int*)d_in[3];
    const int* dst = (const int*)d_in[4];

    int N = in_sizes[0] / 64;
    int E = in_sizes[3];
    int NBUCK = (N + 255) >> BUCK_SHIFT;                 // 256-node buckets
    int C = ((2 * ((E + NBUCK - 1) / NBUCK)) + 255) & ~255;  // bucket capacity
    int nblkA = (E + 4095) / 4096;

    char* p = (char*)d_ws;
    auto alloc = [&](size_t bytes) {
        char* r = p;
        p += (bytes + 255) & ~(size_t)255;
        return r;
    };
    float*    Wf      = (float*)alloc(W_TOTAL * 4);
    uint4*    fragW2  = (uint4*)alloc(4 * 64 * 16);
    uint4*    Abf     = (uint4*)alloc((size_t)N * 64);   // bf16 A rows, 64B
    float*    A2      = (float*)alloc((size_t)N * 32 * 4);
    float*    sumh    = (float*)alloc((size_t)N * 64 * 4);
    int2*     seg     = (int2*)alloc((size_t)N * 8);
    int*      gcnt    = (int*)alloc((size_t)NBUCK * 4);
    unsigned* pairbuf = (unsigned*)alloc((size_t)NBUCK * C * 4);
    int*      ssrc    = (int*)alloc((size_t)NBUCK * C * 4);

    prep_weights<<<32, 256, 0, stream>>>(
        (const float*)d_in[5], (const float*)d_in[6],
        (const float*)d_in[7], (const float*)d_in[8],
        (const float*)d_in[9], (const float*)d_in[10],
        (const float*)d_in[11], (const float*)d_in[12], Wf, fragW2,
        gcnt, NBUCK);

    int nblkP = nblkA + (N + 255) / 256;
    k_phase1<<<nblkP, 256, 0, stream>>>(
        hbuf, ubuf, posbuf, Wf, Abf, A2, src, dst, gcnt, pairbuf, E, N, C, nblkA);

    k_bucketB<<<NBUCK, 256, (size_t)C * 4, stream>>>(
        pairbuf, gcnt, seg, ssrc, N, C);

    const int FBLK = 2048;                    // 8192 waves = full machine
    int npw = (N + FBLK * 4 - 1) / (FBLK * 4);
    fused_edge_gather<<<FBLK, 256, 0, stream>>>(
        seg, ssrc, Abf, posbuf, Wf, fragW2, sumh, N, npw);

    k_node3<<<(N + 127) / 128, 256, 0, stream>>>(
        A2, sumh, Wf, (float*)d_out, N);
}

// Round 10
// 240.628 us; speedup vs baseline: 1.2788x; 1.2465x over previous
//
#include <hip/hip_runtime.h>

// ---------------------------------------------------------------------------
// GNN predictor (fp32 I/O). Round 19 = R9 pipeline with k_node3 replaced by
// k_node4: node MLP as batched MFMA GEMM. 16 nodes/wave-iteration:
//   layer1: S[16x64] x W1T[64x32] = 2 kchunks x 2 Ntiles; layer2:
//   Y[16x32] x W2n[32x64] = 4 Ntiles. Weights preloaded as MFMA B-frags
//   (hi/lo bf16 pairs; 3-term products ~ fp32 accuracy) -> ZERO per-iter
//   weight traffic. 6250 waves (~6/SIMD), tiny per-wave critical path.
//   TANH_SCALE folded into W2 frags + bias. Y redistributed via per-wave
//   LDS tile [16][36] + one barrier.
// R9 LESSON (measured): threadIdx-derived 'half' defeats uniformity
// analysis -> weight loads became per-lane vector loads, k_node3 79us,
// VALUBusy 12%. Scalar-pipe weights need loop-uniform addrs; 1-thread/node
// caps at 1564 waves and ~104 SGPRs can't pipeline 64-float rows. MFMA
// sidesteps both.
// R8 LESSON: __shfl broadcasts + per-lane LDS weight reads = LDS-pipe bound
// (88us). ds_bpermute IS an LDS op.
// R7 LESSON: folding node-MLP into fused costs VGPR 76->124, occ 19%. Split.
// R12/R13 LESSON (R4): per-edge device-scope atomic scatter = ~64B RMW each.
// Keep LDS-aggregated bucket sort.
// R10 LESSON: global-cursor dynamic chunking regressed 4.5x. Static ranges.
// Fused VALU diet (verified R11): tanh scale folded into W2e/b2e;
// sum tanh = deg - 2*sum sigma; pairwise rcp; full/tail batch split.
// ---------------------------------------------------------------------------

#define LRELU_SLOPE 0.01f
#define BUCK_SHIFT 8                  // 256 nodes per bucket
#define TANH_SCALE 2.8853900817779268f  // 2*log2(e)

constexpr int OFF_W1ET  = 0;          // [32][76]  edge W1 transposed
constexpr int OFF_B1E   = 2432;       // [32]
constexpr int OFF_B2E   = 4512;       // [64]      pre-scaled by TANH_SCALE
constexpr int OFF_W1NA  = 4576;       // [32][76]  node W1 (pos,u,h dims) in x76 order
constexpr int OFF_W1NS  = 7008;       // [32][64]  node W1 (sumh dims) transposed
constexpr int OFF_W2N   = 9056;       // [32][64]
constexpr int OFF_B2N   = 11104;      // [64]
constexpr int OFF_B1N   = 11168;      // [32]
constexpr int OFF_W1POS = 11200;      // [32] float2 (W1e rows 2,3)
constexpr int W_TOTAL   = 11264;

typedef __bf16 bf16x8 __attribute__((ext_vector_type(8)));
typedef float  f32x4  __attribute__((ext_vector_type(4)));

__device__ __forceinline__ float ftanh(float x) {
    float e = __builtin_amdgcn_exp2f(x * 2.8853900817779268f);
    return 1.0f - 2.0f * __builtin_amdgcn_rcpf(e + 1.0f);
}
__device__ __forceinline__ unsigned f2bf_pair(float f0, float f1) {
    unsigned u0 = __float_as_uint(f0), u1 = __float_as_uint(f1);
    unsigned r0 = (u0 + 0x7fffu + ((u0 >> 16) & 1u)) >> 16;   // RNE
    unsigned r1 = (u1 + 0x7fffu + ((u1 >> 16) & 1u)) >> 16;
    return r0 | (r1 << 16);
}
__device__ __forceinline__ float bf_lo(unsigned p) { return __uint_as_float(p << 16); }
__device__ __forceinline__ float bf_hi(unsigned p) { return __uint_as_float(p & 0xffff0000u); }
__device__ __forceinline__ float bf_round(float f) {  // f32 value of RNE bf16(f)
    unsigned u = __float_as_uint(f);
    return __uint_as_float((u + 0x7fffu + ((u >> 16) & 1u)) & 0xffff0000u);
}
__device__ __forceinline__ bf16x8 pack8(float a0, float a1, float a2, float a3,
                                        float a4, float a5, float a6, float a7) {
    union { uint4 u; bf16x8 b; } c;
    c.u.x = f2bf_pair(a0, a1); c.u.y = f2bf_pair(a2, a3);
    c.u.z = f2bf_pair(a4, a5); c.u.w = f2bf_pair(a6, a7);
    return c.b;
}

// ---------------------------------------------------------------------------
__global__ void prep_weights(const float* __restrict__ W1e, const float* __restrict__ b1e,
                             const float* __restrict__ W2e, const float* __restrict__ b2e,
                             const float* __restrict__ W1n, const float* __restrict__ b1n,
                             const float* __restrict__ W2n, const float* __restrict__ b2n,
                             float* __restrict__ Wf, uint4* __restrict__ fragW2,
                             uint4* __restrict__ frag1, uint4* __restrict__ frag2,
                             int* __restrict__ gcnt, int nbuck) {
    int t = blockIdx.x * blockDim.x + threadIdx.x;
    int T = gridDim.x * blockDim.x;
    for (int idx = t; idx < nbuck; idx += T) gcnt[idx] = 0;
    for (int idx = t; idx < 2432; idx += T) {            // W1e [76][32] -> [32][76]
        int i = idx / 32, j = idx % 32;
        Wf[OFF_W1ET + j * 76 + i] = W1e[idx];
    }
    for (int idx = t; idx < 32; idx += T)   Wf[OFF_B1E + idx] = b1e[idx];
    for (int idx = t; idx < 64; idx += T)   Wf[OFF_B2E + idx] = b2e[idx] * TANH_SCALE;
    // W1NA[j][i]: node-layer1 weights for x76 = [pos(2),0,0,u(8),h(64)]
    for (int idx = t; idx < 2432; idx += T) {
        int j = idx / 76, i = idx % 76;
        float v = 0.f;
        if (i < 2)                 v = W1n[i * 32 + j];
        else if (i >= 4 && i < 12) v = W1n[(130 + (i - 4)) * 32 + j];
        else if (i >= 12)          v = W1n[(2 + (i - 12)) * 32 + j];
        Wf[OFF_W1NA + idx] = v;
    }
    for (int idx = t; idx < 64; idx += T)   Wf[OFF_B2N + idx] = b2n[idx];
    for (int idx = t; idx < 32; idx += T)   Wf[OFF_B1N + idx] = b1n[idx];
    for (int idx = t; idx < 32; idx += T) {
        Wf[OFF_W1POS + 2 * idx + 0] = W1e[2 * 32 + idx];
        Wf[OFF_W1POS + 2 * idx + 1] = W1e[3 * 32 + idx];
    }
    // MFMA B-fragments for W2e (bf16, pre-scaled), 4 N-tiles x 64 lanes x 16B
    for (int idx = t; idx < 256; idx += T) {
        int tt = idx >> 6, l = idx & 63;
        int colv = l & 15, quadv = l >> 4;
        uint4 v;
        unsigned pk[4];
#pragma unroll
        for (int pr = 0; pr < 4; pr++) {
            int j0 = quadv * 8 + 2 * pr;
            float f0 = W2e[j0 * 64 + 16 * tt + colv] * TANH_SCALE;
            float f1 = W2e[(j0 + 1) * 64 + 16 * tt + colv] * TANH_SCALE;
            pk[pr] = f2bf_pair(f0, f1);
        }
        v.x = pk[0]; v.y = pk[1]; v.z = pk[2]; v.w = pk[3];
        fragW2[tt * 64 + l] = v;
    }
    // node layer-1 B-frags: B[i][j] = W1n[(66+i)*32 + j], hi/lo bf16.
    // frag1[((kc*2+tt)*2+hl)*64 + l]
    for (int idx = t; idx < 512; idx += T) {
        int l = idx & 63, rest = idx >> 6;
        int hl = rest & 1, tt = (rest >> 1) & 1, kc = rest >> 2;
        int colv = l & 15, quadv = l >> 4;
        unsigned pk[4];
#pragma unroll
        for (int pr = 0; pr < 4; pr++) {
            int i0 = kc * 32 + quadv * 8 + 2 * pr;
            float f0 = W1n[(66 + i0) * 32 + tt * 16 + colv];
            float f1 = W1n[(66 + i0 + 1) * 32 + tt * 16 + colv];
            if (hl) { f0 -= bf_round(f0); f1 -= bf_round(f1); }
            pk[pr] = f2bf_pair(f0, f1);
        }
        uint4 v; v.x = pk[0]; v.y = pk[1]; v.z = pk[2]; v.w = pk[3];
        frag1[idx] = v;
    }
    // node layer-2 B-frags: B[j][k] = W2n[j*64 + k] * TANH_SCALE, hi/lo.
    // frag2[(tt*2+hl)*64 + l]
    for (int idx = t; idx < 512; idx += T) {
        int l = idx & 63, rest = idx >> 6;
        int hl = rest & 1, tt = rest >> 1;
        int colv = l & 15, quadv = l >> 4;
        unsigned pk[4];
#pragma unroll
        for (int pr = 0; pr < 4; pr++) {
            int j0 = quadv * 8 + 2 * pr;
            float f0 = W2n[j0 * 64 + tt * 16 + colv] * TANH_SCALE;
            float f1 = W2n[(j0 + 1) * 64 + tt * 16 + colv] * TANH_SCALE;
            if (hl) { f0 -= bf_round(f0); f1 -= bf_round(f1); }
            pk[pr] = f2bf_pair(f0, f1);
        }
        uint4 v; v.x = pk[0]; v.y = pk[1]; v.z = pk[2]; v.w = pk[3];
        frag2[idx] = v;
    }
}

// ---------------------------------------------------------------------------
// Phase 1: bucket-scatter (blocks < nblkA, LDS-aggregated histogram) +
// per-node precompute (rest):
//   Abf[n][32] bf16 : edge-MLP layer1 src part
//   A2 [n][32] f32  : node-MLP layer1 pos/h/u part (+b1n)
// ---------------------------------------------------------------------------
__global__ __launch_bounds__(256) void k_phase1(
    const float* __restrict__ hbuf, const float* __restrict__ ubuf,
    const float* __restrict__ posbuf, const float* __restrict__ Wf,
    uint4* __restrict__ Abf, float* __restrict__ A2,
    const int* __restrict__ src, const int* __restrict__ dst,
    int* __restrict__ gcnt, unsigned* __restrict__ pairbuf,
    int E, int N, int C, int nblkA) {
    __shared__ int cnt[512], base[512];
    int tid = threadIdx.x;
    if ((int)blockIdx.x < nblkA) {
        for (int i = tid; i < 512; i += 256) cnt[i] = 0;
        __syncthreads();
        int e0 = blockIdx.x * 4096;
#pragma unroll
        for (int k = 0; k < 16; k++) {
            int e = e0 + k * 256 + tid;
            if (e < E) atomicAdd(&cnt[dst[e] >> BUCK_SHIFT], 1);
        }
        __syncthreads();
        for (int i = tid; i < 512; i += 256) {
            int c = cnt[i];
            base[i] = (c > 0) ? atomicAdd(&gcnt[i], c) : 0;
            cnt[i] = 0;
        }
        __syncthreads();
#pragma unroll
        for (int k = 0; k < 16; k++) {
            int e = e0 + k * 256 + tid;
            if (e < E) {
                int d = dst[e];
                int b = d >> BUCK_SHIFT;
                int r = base[b] + atomicAdd(&cnt[b], 1);
                if (r < C)
                    pairbuf[(size_t)b * C + r] =
                        (unsigned)src[e] | ((unsigned)(d & 255) << 20);
            }
        }
        return;
    }
    // ---- per-node precompute ----
    int n = (blockIdx.x - nblkA) * 256 + tid;
    if (n >= N) return;
    float x[76];
    float2 pp = ((const float2*)posbuf)[n];
    x[0] = pp.x; x[1] = pp.y; x[2] = 0.f; x[3] = 0.f;
    const float4* u4 = (const float4*)ubuf;
#pragma unroll
    for (int c = 0; c < 2; c++) {
        float4 uu = u4[(size_t)n * 2 + c];
        int b = 4 + 4 * c;
        x[b] = uu.x; x[b + 1] = uu.y; x[b + 2] = uu.z; x[b + 3] = uu.w;
    }
    const float4* h4 = (const float4*)hbuf;
#pragma unroll
    for (int c = 0; c < 16; c++) {
        float4 hh = h4[(size_t)n * 16 + c];
        int b = 12 + 4 * c;
        x[b] = hh.x; x[b + 1] = hh.y; x[b + 2] = hh.z; x[b + 3] = hh.w;
    }
    float ar[32];
#pragma unroll 1
    for (int j = 0; j < 32; j++) {
        const float* w1 = Wf + OFF_W1ET + j * 76;
        float a0 = Wf[OFF_B1E + j], a1 = 0.f, a2 = 0.f, a3 = 0.f;
#pragma unroll
        for (int i = 0; i < 76; i += 4) {
            a0 = fmaf(x[i + 0], w1[i + 0], a0);
            a1 = fmaf(x[i + 1], w1[i + 1], a1);
            a2 = fmaf(x[i + 2], w1[i + 2], a2);
            a3 = fmaf(x[i + 3], w1[i + 3], a3);
        }
        ar[j] = (a0 + a1) + (a2 + a3);
    }
#pragma unroll
    for (int c = 0; c < 4; c++) {
        uint4 v;
        v.x = f2bf_pair(ar[8 * c + 0], ar[8 * c + 1]);
        v.y = f2bf_pair(ar[8 * c + 2], ar[8 * c + 3]);
        v.z = f2bf_pair(ar[8 * c + 4], ar[8 * c + 5]);
        v.w = f2bf_pair(ar[8 * c + 6], ar[8 * c + 7]);
        Abf[(size_t)n * 4 + c] = v;
    }
    // node-MLP layer1 pos/h/u part (x[2],x[3] are zero -> harmless)
#pragma unroll 1
    for (int j = 0; j < 32; j++) {
        const float* w1 = Wf + OFF_W1NA + j * 76;
        float a0 = Wf[OFF_B1N + j], a1 = 0.f, a2 = 0.f, a3 = 0.f;
#pragma unroll
        for (int i = 0; i < 76; i += 4) {
            a0 = fmaf(x[i + 0], w1[i + 0], a0);
            a1 = fmaf(x[i + 1], w1[i + 1], a1);
            a2 = fmaf(x[i + 2], w1[i + 2], a2);
            a3 = fmaf(x[i + 3], w1[i + 3], a3);
        }
        ar[j] = (a0 + a1) + (a2 + a3);
    }
#pragma unroll
    for (int c = 0; c < 8; c++) {
        float4 v; v.x = ar[4 * c]; v.y = ar[4 * c + 1];
        v.z = ar[4 * c + 2]; v.w = ar[4 * c + 3];
        ((float4*)(A2 + (size_t)n * 32))[c] = v;
    }
}

// ---------------------------------------------------------------------------
// Pass B: one block per bucket. LDS deg/scan -> seg; cursor-scatter into
// dynamic LDS; ssrc written COALESCED.
// ---------------------------------------------------------------------------
extern __shared__ unsigned pls[];
__global__ __launch_bounds__(256) void k_bucketB(
    const unsigned* __restrict__ pairbuf, const int* __restrict__ gcnt,
    int2* __restrict__ seg, int* __restrict__ ssrc, int N, int C) {
    __shared__ int deg[256], scn[256], exc[256], cur[256];
    int b = blockIdx.x, tid = threadIdx.x;
    int cntb = gcnt[b];
    cntb = (cntb < C) ? cntb : C;
    deg[tid] = 0; cur[tid] = 0;
    __syncthreads();
    size_t basep = (size_t)b * C;
    for (int i = tid; i < cntb; i += 256)
        atomicAdd(&deg[pairbuf[basep + i] >> 20], 1);
    __syncthreads();
    scn[tid] = deg[tid];
    __syncthreads();
    for (int st = 1; st < 256; st <<= 1) {
        int add = (tid >= st) ? scn[tid - st] : 0;
        __syncthreads();
        scn[tid] += add;
        __syncthreads();
    }
    int ex = scn[tid] - deg[tid];
    exc[tid] = ex;
    int n = (b << BUCK_SHIFT) + tid;
    if (n < N) {
        int lo = b * C + ex;
        seg[n] = make_int2(lo, lo + deg[tid]);
    }
    __syncthreads();
    // scatter into LDS (pairbuf re-read is L2-hot)
    for (int i = tid; i < cntb; i += 256) {
        unsigned p = pairbuf[basep + i];
        int l = (int)(p >> 20);
        int slot = exc[l] + atomicAdd(&cur[l], 1);
        pls[slot] = p & 0xFFFFFu;
    }
    __syncthreads();
    for (int i = tid; i < cntb; i += 256)
        ssrc[basep + i] = (int)pls[i];
}

// ---------------------------------------------------------------------------
// Fused edge-MLP + gather (EXACT R11/R2 verified 69.2us kernel).
// ---------------------------------------------------------------------------
__global__ __launch_bounds__(256) void fused_edge_gather(
    const int2* __restrict__ seg, const int* __restrict__ ssrc,
    const uint4* __restrict__ Abf, const float* __restrict__ posbuf,
    const float* __restrict__ Wf, const uint4* __restrict__ fragW2,
    float* __restrict__ sumh, int N, int npw) {
    int wid = blockIdx.x * 4 + (threadIdx.x >> 6);
    int lane = threadIdx.x & 63;
    int col = lane & 15, quad = lane >> 4;

    union { uint4 u; bf16x8 v; } cvt;
    bf16x8 bfr[4];
#pragma unroll
    for (int t = 0; t < 4; t++) {
        cvt.u = fragW2[t * 64 + lane];
        bfr[t] = cvt.v;
    }
    float c0[4];
#pragma unroll
    for (int t = 0; t < 4; t++) c0[t] = Wf[OFF_B2E + 16 * t + col];
    float wx[8], wy[8];
#pragma unroll
    for (int jj = 0; jj < 8; jj++) {
        float2 wv = ((const float2*)(Wf + OFF_W1POS))[quad * 8 + jj];
        wx[jj] = wv.x; wy[jj] = wv.y;
    }

    int n0 = wid * npw;
    int n1 = n0 + npw; n1 = (n1 < N) ? n1 : N;
#pragma unroll 1
    for (int n = n0; n < n1; n++) {
        int2 sg = seg[n];
        int lo = sg.x, hi = sg.y, deg = hi - lo;
        float2 pd = ((const float2*)posbuf)[n];
        float padd[8];
#pragma unroll
        for (int jj = 0; jj < 8; jj++)
            padd[jj] = fmaf(pd.x, wx[jj], pd.y * wy[jj]);

        float s0[4] = {0.f, 0.f, 0.f, 0.f};
        if (deg > 0) {
            int te = lo + col;
            te = (te < hi) ? te : (hi - 1);
            uint4 ar = Abf[(size_t)ssrc[te] * 4 + quad];
            int nfull = deg & ~15;
#pragma unroll 1
            for (int b = 0; b < nfull; b += 16) {
                // prefetch next batch (clamped; harmless re-read at the end)
                int teN = lo + b + 16 + col;
                teN = (teN < hi) ? teN : (hi - 1);
                uint4 arN = Abf[(size_t)ssrc[teN] * 4 + quad];

                bf16x8 af;
                {
                    float v0 = bf_lo(ar.x) + padd[0], v1 = bf_hi(ar.x) + padd[1];
                    float v2 = bf_lo(ar.y) + padd[2], v3 = bf_hi(ar.y) + padd[3];
                    float v4 = bf_lo(ar.z) + padd[4], v5 = bf_hi(ar.z) + padd[5];
                    float v6 = bf_lo(ar.w) + padd[6], v7 = bf_hi(ar.w) + padd[7];
                    v0 = fmaxf(v0, LRELU_SLOPE * v0); v1 = fmaxf(v1, LRELU_SLOPE * v1);
                    v2 = fmaxf(v2, LRELU_SLOPE * v2); v3 = fmaxf(v3, LRELU_SLOPE * v3);
                    v4 = fmaxf(v4, LRELU_SLOPE * v4); v5 = fmaxf(v5, LRELU_SLOPE * v5);
                    v6 = fmaxf(v6, LRELU_SLOPE * v6); v7 = fmaxf(v7, LRELU_SLOPE * v7);
                    af[0] = (__bf16)v0; af[1] = (__bf16)v1; af[2] = (__bf16)v2; af[3] = (__bf16)v3;
                    af[4] = (__bf16)v4; af[5] = (__bf16)v5; af[6] = (__bf16)v6; af[7] = (__bf16)v7;
                }
#pragma unroll
                for (int t = 0; t < 4; t++) {
                    f32x4 acc = {c0[t], c0[t], c0[t], c0[t]};
                    acc = __builtin_amdgcn_mfma_f32_16x16x32_bf16(af, bfr[t], acc, 0, 0, 0);
                    float u0 = __builtin_amdgcn_exp2f(acc[0]);
                    float u1 = __builtin_amdgcn_exp2f(acc[1]);
                    float u2 = __builtin_amdgcn_exp2f(acc[2]);
                    float u3 = __builtin_amdgcn_exp2f(acc[3]);
                    float q01 = u0 + u1, q23 = u2 + u3;
                    float d01 = fmaf(u0, u1, q01) + 1.f;
                    float d23 = fmaf(u2, u3, q23) + 1.f;
                    s0[t] = fmaf(q01 + 2.f, __builtin_amdgcn_rcpf(d01), s0[t]);
                    s0[t] = fmaf(q23 + 2.f, __builtin_amdgcn_rcpf(d23), s0[t]);
                }
                ar = arN;
            }
            int tail = deg - nfull;
            if (tail) {
                bf16x8 af;
                {
                    float v0 = bf_lo(ar.x) + padd[0], v1 = bf_hi(ar.x) + padd[1];
                    float v2 = bf_lo(ar.y) + padd[2], v3 = bf_hi(ar.y) + padd[3];
                    float v4 = bf_lo(ar.z) + padd[4], v5 = bf_hi(ar.z) + padd[5];
                    float v6 = bf_lo(ar.w) + padd[6], v7 = bf_hi(ar.w) + padd[7];
                    v0 = fmaxf(v0, LRELU_SLOPE * v0); v1 = fmaxf(v1, LRELU_SLOPE * v1);
                    v2 = fmaxf(v2, LRELU_SLOPE * v2); v3 = fmaxf(v3, LRELU_SLOPE * v3);
                    v4 = fmaxf(v4, LRELU_SLOPE * v4); v5 = fmaxf(v5, LRELU_SLOPE * v5);
                    v6 = fmaxf(v6, LRELU_SLOPE * v6); v7 = fmaxf(v7, LRELU_SLOPE * v7);
                    af[0] = (__bf16)v0; af[1] = (__bf16)v1; af[2] = (__bf16)v2; af[3] = (__bf16)v3;
                    af[4] = (__bf16)v4; af[5] = (__bf16)v5; af[6] = (__bf16)v6; af[7] = (__bf16)v7;
                }
                int rowb = quad * 4;
#pragma unroll
                for (int t = 0; t < 4; t++) {
                    f32x4 acc = {c0[t], c0[t], c0[t], c0[t]};
                    acc = __builtin_amdgcn_mfma_f32_16x16x32_bf16(af, bfr[t], acc, 0, 0, 0);
                    // invalid rows: u = 1e30 -> pair algebra makes the
                    // contribution ~2^-60 (drops out); double-invalid ~0.
                    float u0 = (rowb + 0 < tail) ? __builtin_amdgcn_exp2f(acc[0]) : 1e30f;
                    float u1 = (rowb + 1 < tail) ? __builtin_amdgcn_exp2f(acc[1]) : 1e30f;
                    float u2 = (rowb + 2 < tail) ? __builtin_amdgcn_exp2f(acc[2]) : 1e30f;
                    float u3 = (rowb + 3 < tail) ? __builtin_amdgcn_exp2f(acc[3]) : 1e30f;
                    float q01 = u0 + u1, q23 = u2 + u3;
                    float d01 = fmaf(u0, u1, q01) + 1.f;
                    float d23 = fmaf(u2, u3, q23) + 1.f;
                    s0[t] = fmaf(q01 + 2.f, __builtin_amdgcn_rcpf(d01), s0[t]);
                    s0[t] = fmaf(q23 + 2.f, __builtin_amdgcn_rcpf(d23), s0[t]);
                }
            }
        }
#pragma unroll
        for (int t = 0; t < 4; t++) {
            s0[t] += __shfl_xor(s0[t], 16);
            s0[t] += __shfl_xor(s0[t], 32);
        }
        if (lane < 16) {
            float* sr = sumh + (size_t)n * 64;
            float fd = (float)deg;
#pragma unroll
            for (int t = 0; t < 4; t++) sr[16 * t + lane] = fmaf(-2.f, s0[t], fd);
        }
    }
}

// ---------------------------------------------------------------------------
// Node MLP via MFMA: 16 nodes per wave. layer1 = S(16x64) x W1T(64x32),
// layer2 = Y(16x32) x W2n(32x64). hi/lo bf16 3-term products ~ fp32.
// Y redistributed (C-layout -> A-layout) through a per-wave LDS tile.
// ---------------------------------------------------------------------------
__global__ __launch_bounds__(256) void k_node4(
    const float* __restrict__ A2, const float* __restrict__ sumh,
    const float* __restrict__ Wf, const uint4* __restrict__ frag1,
    const uint4* __restrict__ frag2, float* __restrict__ out,
    int N, int ngroups) {
    __shared__ float ylds[4 * 16 * 36];   // per-wave [16 nodes][32 y + pad4]
    int wv = threadIdx.x >> 6, lane = threadIdx.x & 63;
    int col = lane & 15, quad = lane >> 4;
    int g = blockIdx.x * 4 + wv;
    bool live = (g < ngroups);
    int gc = live ? g : (ngroups - 1);
    int nbase = gc * 16;

    // ---- S A-frags (hi/lo), 2 k-chunks: lane = (node=col, k=quad*8..+8) ----
    int nA = nbase + col; nA = (nA < N) ? nA : (N - 1);
    const float* srow = sumh + (size_t)nA * 64 + quad * 8;
    bf16x8 sh[2], sl[2];
#pragma unroll
    for (int kc = 0; kc < 2; kc++) {
        float4 f0 = *(const float4*)(srow + kc * 32);
        float4 f1 = *(const float4*)(srow + kc * 32 + 4);
        sh[kc] = pack8(f0.x, f0.y, f0.z, f0.w, f1.x, f1.y, f1.z, f1.w);
        sl[kc] = pack8(f0.x - bf_round(f0.x), f0.y - bf_round(f0.y),
                       f0.z - bf_round(f0.z), f0.w - bf_round(f0.w),
                       f1.x - bf_round(f1.x), f1.y - bf_round(f1.y),
                       f1.z - bf_round(f1.z), f1.w - bf_round(f1.w));
    }

    // ---- layer 1: acc1[t] = S x W1T (2 N-tiles) ----
    f32x4 acc1[2];
#pragma unroll
    for (int t = 0; t < 2; t++) { f32x4 z = {0.f, 0.f, 0.f, 0.f}; acc1[t] = z; }
#pragma unroll
    for (int kc = 0; kc < 2; kc++) {
#pragma unroll
        for (int t = 0; t < 2; t++) {
            union { uint4 u; bf16x8 b; } bh, bl;
            bh.u = frag1[((kc * 2 + t) * 2 + 0) * 64 + lane];
            bl.u = frag1[((kc * 2 + t) * 2 + 1) * 64 + lane];
            acc1[t] = __builtin_amdgcn_mfma_f32_16x16x32_bf16(sh[kc], bh.b, acc1[t], 0, 0, 0);
            acc1[t] = __builtin_amdgcn_mfma_f32_16x16x32_bf16(sh[kc], bl.b, acc1[t], 0, 0, 0);
            acc1[t] = __builtin_amdgcn_mfma_f32_16x16x32_bf16(sl[kc], bh.b, acc1[t], 0, 0, 0);
        }
    }

    // ---- +A2, lrelu, stash Y in LDS (C layout: node=quad*4+r, j=16t+col) ----
    float* yw = ylds + wv * 576;
#pragma unroll
    for (int t = 0; t < 2; t++) {
#pragma unroll
        for (int r = 0; r < 4; r++) {
            int ndr = quad * 4 + r;
            int nd = nbase + ndr; nd = (nd < N) ? nd : (N - 1);
            float yv = acc1[t][r] + A2[(size_t)nd * 32 + t * 16 + col];
            yv = fmaxf(yv, LRELU_SLOPE * yv);
            yw[ndr * 36 + t * 16 + col] = yv;
        }
    }
    __syncthreads();   // orders own-wave LDS writes -> reads (and block)

    // ---- Y A-frag (hi/lo): lane = (node=col, k=quad*8..+8) ----
    const float* yr = ylds + wv * 576 + col * 36 + quad * 8;
    float4 y0 = *(const float4*)(yr);
    float4 y1 = *(const float4*)(yr + 4);
    bf16x8 yh = pack8(y0.x, y0.y, y0.z, y0.w, y1.x, y1.y, y1.z, y1.w);
    bf16x8 yl = pack8(y0.x - bf_round(y0.x), y0.y - bf_round(y0.y),
                      y0.z - bf_round(y0.z), y0.w - bf_round(y0.w),
                      y1.x - bf_round(y1.x), y1.y - bf_round(y1.y),
                      y1.z - bf_round(y1.z), y1.w - bf_round(y1.w));

    // ---- layer 2: acc2[t] = Y x W2n + b2n (scaled); tanh; store ----
    f32x4 acc2[4];
#pragma unroll
    for (int t = 0; t < 4; t++) {
        float b = Wf[OFF_B2N + t * 16 + col] * TANH_SCALE;
        f32x4 z = {b, b, b, b}; acc2[t] = z;
    }
#pragma unroll
    for (int t = 0; t < 4; t++) {
        union { uint4 u; bf16x8 b; } bh, bl;
        bh.u = frag2[(t * 2 + 0) * 64 + lane];
        bl.u = frag2[(t * 2 + 1) * 64 + lane];
        acc2[t] = __builtin_amdgcn_mfma_f32_16x16x32_bf16(yh, bh.b, acc2[t], 0, 0, 0);
        acc2[t] = __builtin_amdgcn_mfma_f32_16x16x32_bf16(yh, bl.b, acc2[t], 0, 0, 0);
        acc2[t] = __builtin_amdgcn_mfma_f32_16x16x32_bf16(yl, bh.b, acc2[t], 0, 0, 0);
    }
    if (live) {
#pragma unroll
        for (int t = 0; t < 4; t++) {
#pragma unroll
            for (int r = 0; r < 4; r++) {
                int nd = nbase + quad * 4 + r;
                if (nd < N) {
                    float e = __builtin_amdgcn_exp2f(acc2[t][r]);
                    out[(size_t)nd * 64 + t * 16 + col] =
                        1.f - 2.f * __builtin_amdgcn_rcpf(e + 1.f);
                }
            }
        }
    }
}

// ---------------------------------------------------------------------------
extern "C" void kernel_launch(void* const* d_in, const int* in_sizes, int n_in,
                              void* d_out, int out_size, void* d_ws, size_t ws_size,
                              hipStream_t stream) {
    const float* hbuf   = (const float*)d_in[0];
    const float* ubuf   = (const float*)d_in[1];
    const float* posbuf = (const float*)d_in[2];
    const int* src = (const int*)d_in[3];
    const int* dst = (const int*)d_in[4];

    int N = in_sizes[0] / 64;
    int E = in_sizes[3];
    int NBUCK = (N + 255) >> BUCK_SHIFT;                 // 256-node buckets
    int C = ((2 * ((E + NBUCK - 1) / NBUCK)) + 255) & ~255;  // bucket capacity
    int nblkA = (E + 4095) / 4096;

    char* p = (char*)d_ws;
    auto alloc = [&](size_t bytes) {
        char* r = p;
        p += (bytes + 255) & ~(size_t)255;
        return r;
    };
    float*    Wf      = (float*)alloc(W_TOTAL * 4);
    uint4*    fragW2  = (uint4*)alloc(4 * 64 * 16);
    uint4*    frag1   = (uint4*)alloc(512 * 16);
    uint4*    frag2   = (uint4*)alloc(512 * 16);
    uint4*    Abf     = (uint4*)alloc((size_t)N * 64);   // bf16 A rows, 64B
    float*    A2      = (float*)alloc((size_t)N * 32 * 4);
    float*    sumh    = (float*)alloc((size_t)N * 64 * 4);
    int2*     seg     = (int2*)alloc((size_t)N * 8);
    int*      gcnt    = (int*)alloc((size_t)NBUCK * 4);
    unsigned* pairbuf = (unsigned*)alloc((size_t)NBUCK * C * 4);
    int*      ssrc    = (int*)alloc((size_t)NBUCK * C * 4);

    prep_weights<<<32, 256, 0, stream>>>(
        (const float*)d_in[5], (const float*)d_in[6],
        (const float*)d_in[7], (const float*)d_in[8],
        (const float*)d_in[9], (const float*)d_in[10],
        (const float*)d_in[11], (const float*)d_in[12], Wf, fragW2,
        frag1, frag2, gcnt, NBUCK);

    int nblkP = nblkA + (N + 255) / 256;
    k_phase1<<<nblkP, 256, 0, stream>>>(
        hbuf, ubuf, posbuf, Wf, Abf, A2, src, dst, gcnt, pairbuf, E, N, C, nblkA);

    k_bucketB<<<NBUCK, 256, (size_t)C * 4, stream>>>(
        pairbuf, gcnt, seg, ssrc, N, C);

    const int FBLK = 2048;                    // 8192 waves = full machine
    int npw = (N + FBLK * 4 - 1) / (FBLK * 4);
    fused_edge_gather<<<FBLK, 256, 0, stream>>>(
        seg, ssrc, Abf, posbuf, Wf, fragW2, sumh, N, npw);

    int ngroups = (N + 15) / 16;
    k_node4<<<(ngroups + 3) / 4, 256, 0, stream>>>(
        A2, sumh, Wf, frag1, frag2, (float*)d_out, N, ngroups);
}

// Round 11
// 235.402 us; speedup vs baseline: 1.3072x; 1.0222x over previous
//
#include <hip/hip_runtime.h>

// ---------------------------------------------------------------------------
// GNN predictor (fp32 I/O). Round 20 = R19 (240.6us: fused 70.5 + node4 ~19
// + phase1/bucketB ~145) with the R19-proven MFMA recipe applied to phase1:
//   - phase1 precompute -> MFMA, 16 nodes/wave: X96 = [h(64)|pos,0,0,u(8),
//     0..0]; edge-layer1 (->Abf) and node-layer1 (->A2) each = 3 kchunks x
//     2 Ntiles x (hi/lo 3-term) MFMAs with preloaded B-frags; biases in
//     acc init; outputs repacked via per-wave LDS tiles. Kills the serial
//     9728-FMA/thread chain (k_node2-shaped, ~60us at 391 blocks).
//   - scatter chunks 4096->2048 edges (782 blocks, 2x latency hiding)
//   - k_bucketB 256->512 threads (8 waves/bucket; scan on tid<256)
// R19 LESSON (measured): MFMA + preloaded frags + hi/lo bf16 3-term fixed
// the node MLP (58->~19us). Scalar-pipe-weight kernels at ~1.5 blocks/CU
// are latency-bound regardless of arithmetic.
// R9 LESSON: threadIdx-derived splits defeat uniformity -> vector loads.
// R8 LESSON: __shfl/ds_bpermute broadcasts are LDS-pipe ops; avoid in bulk.
// R7 LESSON: folding node-MLP into fused costs VGPR/occupancy. Keep split.
// R12/R13 LESSON (R4): per-edge device-scope atomic scatter = ~64B RMW.
// Keep LDS-aggregated bucket sort.
// R10 LESSON: global-cursor dynamic chunking regressed 4.5x. Static ranges.
// Fused VALU diet (verified R11): tanh scale folded into W2e/b2e;
// sum tanh = deg - 2*sum sigma; pairwise rcp; full/tail batch split.
// ---------------------------------------------------------------------------

#define LRELU_SLOPE 0.01f
#define BUCK_SHIFT 8                  // 256 nodes per bucket
#define TANH_SCALE 2.8853900817779268f  // 2*log2(e)

constexpr int OFF_B1E   = 2432;       // [32]
constexpr int OFF_B2E   = 4512;       // [64]      pre-scaled by TANH_SCALE
constexpr int OFF_B2N   = 11104;      // [64]
constexpr int OFF_B1N   = 11168;      // [32]
constexpr int OFF_W1POS = 11200;      // [32] float2 (W1e rows 2,3)
constexpr int W_TOTAL   = 11264;

typedef __bf16 bf16x8 __attribute__((ext_vector_type(8)));
typedef float  f32x4  __attribute__((ext_vector_type(4)));

__device__ __forceinline__ unsigned f2bf_pair(float f0, float f1) {
    unsigned u0 = __float_as_uint(f0), u1 = __float_as_uint(f1);
    unsigned r0 = (u0 + 0x7fffu + ((u0 >> 16) & 1u)) >> 16;   // RNE
    unsigned r1 = (u1 + 0x7fffu + ((u1 >> 16) & 1u)) >> 16;
    return r0 | (r1 << 16);
}
__device__ __forceinline__ float bf_lo(unsigned p) { return __uint_as_float(p << 16); }
__device__ __forceinline__ float bf_hi(unsigned p) { return __uint_as_float(p & 0xffff0000u); }
__device__ __forceinline__ float bf_round(float f) {  // f32 value of RNE bf16(f)
    unsigned u = __float_as_uint(f);
    return __uint_as_float((u + 0x7fffu + ((u >> 16) & 1u)) & 0xffff0000u);
}
__device__ __forceinline__ bf16x8 pack8(float a0, float a1, float a2, float a3,
                                        float a4, float a5, float a6, float a7) {
    union { uint4 u; bf16x8 b; } c;
    c.u.x = f2bf_pair(a0, a1); c.u.y = f2bf_pair(a2, a3);
    c.u.z = f2bf_pair(a4, a5); c.u.w = f2bf_pair(a6, a7);
    return c.b;
}

// X96 row maps: X = [h(64) | pos.x,pos.y,0,0,u(8),0*20]
__device__ __forceinline__ float w1e_x96(const float* W1e, int i, int j) {
    // edge_inp rows: 0-1 pos_src, 2-3 pos_dst (per-edge), 4-11 u, 12-75 h
    if (i < 64) return W1e[(12 + i) * 32 + j];
    if (i == 64) return W1e[0 * 32 + j];
    if (i == 65) return W1e[1 * 32 + j];
    if (i >= 68 && i < 76) return W1e[(4 + i - 68) * 32 + j];
    return 0.f;
}
__device__ __forceinline__ float w1n_x96(const float* W1n, int i, int j) {
    // node_inp rows: 0-1 pos, 2-65 h, 66-129 sumh (separate GEMM), 130-137 u
    if (i < 64) return W1n[(2 + i) * 32 + j];
    if (i == 64) return W1n[0 * 32 + j];
    if (i == 65) return W1n[1 * 32 + j];
    if (i >= 68 && i < 76) return W1n[(130 + i - 68) * 32 + j];
    return 0.f;
}

// ---------------------------------------------------------------------------
__global__ void prep_weights(const float* __restrict__ W1e, const float* __restrict__ b1e,
                             const float* __restrict__ W2e, const float* __restrict__ b2e,
                             const float* __restrict__ W1n, const float* __restrict__ b1n,
                             const float* __restrict__ W2n, const float* __restrict__ b2n,
                             float* __restrict__ Wf, uint4* __restrict__ fragW2,
                             uint4* __restrict__ frag1, uint4* __restrict__ frag2,
                             uint4* __restrict__ fragE, uint4* __restrict__ fragN,
                             int* __restrict__ gcnt, int nbuck) {
    int t = blockIdx.x * blockDim.x + threadIdx.x;
    int T = gridDim.x * blockDim.x;
    for (int idx = t; idx < nbuck; idx += T) gcnt[idx] = 0;
    for (int idx = t; idx < 32; idx += T)   Wf[OFF_B1E + idx] = b1e[idx];
    for (int idx = t; idx < 64; idx += T)   Wf[OFF_B2E + idx] = b2e[idx] * TANH_SCALE;
    for (int idx = t; idx < 64; idx += T)   Wf[OFF_B2N + idx] = b2n[idx];
    for (int idx = t; idx < 32; idx += T)   Wf[OFF_B1N + idx] = b1n[idx];
    for (int idx = t; idx < 32; idx += T) {
        Wf[OFF_W1POS + 2 * idx + 0] = W1e[2 * 32 + idx];
        Wf[OFF_W1POS + 2 * idx + 1] = W1e[3 * 32 + idx];
    }
    // MFMA B-fragments for W2e (bf16, pre-scaled), 4 N-tiles x 64 lanes x 16B
    for (int idx = t; idx < 256; idx += T) {
        int tt = idx >> 6, l = idx & 63;
        int colv = l & 15, quadv = l >> 4;
        uint4 v;
        unsigned pk[4];
#pragma unroll
        for (int pr = 0; pr < 4; pr++) {
            int j0 = quadv * 8 + 2 * pr;
            float f0 = W2e[j0 * 64 + 16 * tt + colv] * TANH_SCALE;
            float f1 = W2e[(j0 + 1) * 64 + 16 * tt + colv] * TANH_SCALE;
            pk[pr] = f2bf_pair(f0, f1);
        }
        v.x = pk[0]; v.y = pk[1]; v.z = pk[2]; v.w = pk[3];
        fragW2[tt * 64 + l] = v;
    }
    // node layer-1 B-frags (sumh part): B[i][j] = W1n[(66+i)*32+j], hi/lo
    for (int idx = t; idx < 512; idx += T) {
        int l = idx & 63, rest = idx >> 6;
        int hl = rest & 1, tt = (rest >> 1) & 1, kc = rest >> 2;
        int colv = l & 15, quadv = l >> 4;
        unsigned pk[4];
#pragma unroll
        for (int pr = 0; pr < 4; pr++) {
            int i0 = kc * 32 + quadv * 8 + 2 * pr;
            float f0 = W1n[(66 + i0) * 32 + tt * 16 + colv];
            float f1 = W1n[(66 + i0 + 1) * 32 + tt * 16 + colv];
            if (hl) { f0 -= bf_round(f0); f1 -= bf_round(f1); }
            pk[pr] = f2bf_pair(f0, f1);
        }
        uint4 v; v.x = pk[0]; v.y = pk[1]; v.z = pk[2]; v.w = pk[3];
        frag1[idx] = v;
    }
    // node layer-2 B-frags: B[j][k] = W2n[j*64+k]*TANH_SCALE, hi/lo
    for (int idx = t; idx < 512; idx += T) {
        int l = idx & 63, rest = idx >> 6;
        int hl = rest & 1, tt = rest >> 1;
        int colv = l & 15, quadv = l >> 4;
        unsigned pk[4];
#pragma unroll
        for (int pr = 0; pr < 4; pr++) {
            int j0 = quadv * 8 + 2 * pr;
            float f0 = W2n[j0 * 64 + tt * 16 + colv] * TANH_SCALE;
            float f1 = W2n[(j0 + 1) * 64 + tt * 16 + colv] * TANH_SCALE;
            if (hl) { f0 -= bf_round(f0); f1 -= bf_round(f1); }
            pk[pr] = f2bf_pair(f0, f1);
        }
        uint4 v; v.x = pk[0]; v.y = pk[1]; v.z = pk[2]; v.w = pk[3];
        frag2[idx] = v;
    }
    // phase1 precompute B-frags over X96: fragE (edge layer1), fragN (node
    // layer1 pos/h/u part). [kc(3)][tt(2)][hl(2)][64]
    for (int idx = t; idx < 768; idx += T) {
        int l = idx & 63, rest = idx >> 6;
        int hl = rest & 1, tt = (rest >> 1) & 1, kc = rest >> 2;
        int colv = l & 15, quadv = l >> 4;
        int j = tt * 16 + colv;
        unsigned pkE[4], pkN[4];
#pragma unroll
        for (int pr = 0; pr < 4; pr++) {
            int i0 = kc * 32 + quadv * 8 + 2 * pr;
            float e0 = w1e_x96(W1e, i0, j), e1 = w1e_x96(W1e, i0 + 1, j);
            float n0 = w1n_x96(W1n, i0, j), n1 = w1n_x96(W1n, i0 + 1, j);
            if (hl) {
                e0 -= bf_round(e0); e1 -= bf_round(e1);
                n0 -= bf_round(n0); n1 -= bf_round(n1);
            }
            pkE[pr] = f2bf_pair(e0, e1);
            pkN[pr] = f2bf_pair(n0, n1);
        }
        uint4 ve; ve.x = pkE[0]; ve.y = pkE[1]; ve.z = pkE[2]; ve.w = pkE[3];
        uint4 vn; vn.x = pkN[0]; vn.y = pkN[1]; vn.z = pkN[2]; vn.w = pkN[3];
        fragE[idx] = ve;
        fragN[idx] = vn;
    }
}

// ---------------------------------------------------------------------------
// Phase 1: bucket-scatter (blocks < nblkA, 2048 edges/block, LDS-aggregated
// histogram) + MFMA per-node precompute (rest, 16 nodes/wave):
//   Abf[n][32] bf16 : edge-MLP layer1 src part
//   A2 [n][32] f32  : node-MLP layer1 pos/h/u part (+b1n)
// ---------------------------------------------------------------------------
__global__ __launch_bounds__(256) void k_phase1(
    const float* __restrict__ hbuf, const float* __restrict__ ubuf,
    const float* __restrict__ posbuf, const float* __restrict__ Wf,
    const uint4* __restrict__ fragE, const uint4* __restrict__ fragN,
    uint4* __restrict__ Abf, float* __restrict__ A2,
    const int* __restrict__ src, const int* __restrict__ dst,
    int* __restrict__ gcnt, unsigned* __restrict__ pairbuf,
    int E, int N, int C, int nblkA) {
    __shared__ int cnt[512], base[512];
    __shared__ float tileE[4 * 16 * 36], tileN[4 * 16 * 36];
    int tid = threadIdx.x;
    if ((int)blockIdx.x < nblkA) {
        for (int i = tid; i < 512; i += 256) cnt[i] = 0;
        __syncthreads();
        int e0 = blockIdx.x * 2048;
#pragma unroll
        for (int k = 0; k < 8; k++) {
            int e = e0 + k * 256 + tid;
            if (e < E) atomicAdd(&cnt[dst[e] >> BUCK_SHIFT], 1);
        }
        __syncthreads();
        for (int i = tid; i < 512; i += 256) {
            int c = cnt[i];
            base[i] = (c > 0) ? atomicAdd(&gcnt[i], c) : 0;
            cnt[i] = 0;
        }
        __syncthreads();
#pragma unroll
        for (int k = 0; k < 8; k++) {
            int e = e0 + k * 256 + tid;
            if (e < E) {
                int d = dst[e];
                int b = d >> BUCK_SHIFT;
                int r = base[b] + atomicAdd(&cnt[b], 1);
                if (r < C)
                    pairbuf[(size_t)b * C + r] =
                        (unsigned)src[e] | ((unsigned)(d & 255) << 20);
            }
        }
        return;
    }
    // ---- MFMA per-node precompute: 16 nodes per wave ----
    int wv = tid >> 6, lane = tid & 63;
    int col = lane & 15, quad = lane >> 4;
    int g = ((int)blockIdx.x - nblkA) * 4 + wv;
    int ngroups = (N + 15) >> 4;
    if (g >= ngroups) return;
    int nbase = g * 16;
    int nA = nbase + col; nA = (nA < N) ? nA : (N - 1);

    // A-frags (hi/lo): lane = (node=col, k = quad*8..+8) per k-chunk
    bf16x8 xh[3], xl[3];
    {
        const float* hrow = hbuf + (size_t)nA * 64 + quad * 8;
        float4 f0 = *(const float4*)(hrow);
        float4 f1 = *(const float4*)(hrow + 4);
        xh[0] = pack8(f0.x, f0.y, f0.z, f0.w, f1.x, f1.y, f1.z, f1.w);
        xl[0] = pack8(f0.x - bf_round(f0.x), f0.y - bf_round(f0.y),
                      f0.z - bf_round(f0.z), f0.w - bf_round(f0.w),
                      f1.x - bf_round(f1.x), f1.y - bf_round(f1.y),
                      f1.z - bf_round(f1.z), f1.w - bf_round(f1.w));
        float4 g0 = *(const float4*)(hrow + 32);
        float4 g1 = *(const float4*)(hrow + 36);
        xh[1] = pack8(g0.x, g0.y, g0.z, g0.w, g1.x, g1.y, g1.z, g1.w);
        xl[1] = pack8(g0.x - bf_round(g0.x), g0.y - bf_round(g0.y),
                      g0.z - bf_round(g0.z), g0.w - bf_round(g0.w),
                      g1.x - bf_round(g1.x), g1.y - bf_round(g1.y),
                      g1.z - bf_round(g1.z), g1.w - bf_round(g1.w));
    }
    {
        float xv[8];
#pragma unroll
        for (int i = 0; i < 8; i++) xv[i] = 0.f;
        if (quad == 0) {
            float2 pp = ((const float2*)posbuf)[nA];
            float4 uu = ((const float4*)ubuf)[(size_t)nA * 2];
            xv[0] = pp.x; xv[1] = pp.y;
            xv[4] = uu.x; xv[5] = uu.y; xv[6] = uu.z; xv[7] = uu.w;
        } else if (quad == 1) {
            float4 ub = ((const float4*)ubuf)[(size_t)nA * 2 + 1];
            xv[0] = ub.x; xv[1] = ub.y; xv[2] = ub.z; xv[3] = ub.w;
        }
        xh[2] = pack8(xv[0], xv[1], xv[2], xv[3], xv[4], xv[5], xv[6], xv[7]);
        xl[2] = pack8(xv[0] - bf_round(xv[0]), xv[1] - bf_round(xv[1]),
                      xv[2] - bf_round(xv[2]), xv[3] - bf_round(xv[3]),
                      xv[4] - bf_round(xv[4]), xv[5] - bf_round(xv[5]),
                      xv[6] - bf_round(xv[6]), xv[7] - bf_round(xv[7]));
    }

    f32x4 accE[2], accN[2];
#pragma unroll
    for (int t = 0; t < 2; t++) {
        float be = Wf[OFF_B1E + t * 16 + col];
        float bn = Wf[OFF_B1N + t * 16 + col];
        f32x4 e = {be, be, be, be}; accE[t] = e;
        f32x4 n = {bn, bn, bn, bn}; accN[t] = n;
    }
#pragma unroll
    for (int kc = 0; kc < 3; kc++) {
#pragma unroll
        for (int t = 0; t < 2; t++) {
            union { uint4 u; bf16x8 b; } bh, bl;
            int fi = ((kc * 2 + t) * 2) * 64 + lane;
            bh.u = fragE[fi]; bl.u = fragE[fi + 64];
            accE[t] = __builtin_amdgcn_mfma_f32_16x16x32_bf16(xh[kc], bh.b, accE[t], 0, 0, 0);
            accE[t] = __builtin_amdgcn_mfma_f32_16x16x32_bf16(xh[kc], bl.b, accE[t], 0, 0, 0);
            accE[t] = __builtin_amdgcn_mfma_f32_16x16x32_bf16(xl[kc], bh.b, accE[t], 0, 0, 0);
            bh.u = fragN[fi]; bl.u = fragN[fi + 64];
            accN[t] = __builtin_amdgcn_mfma_f32_16x16x32_bf16(xh[kc], bh.b, accN[t], 0, 0, 0);
            accN[t] = __builtin_amdgcn_mfma_f32_16x16x32_bf16(xh[kc], bl.b, accN[t], 0, 0, 0);
            accN[t] = __builtin_amdgcn_mfma_f32_16x16x32_bf16(xl[kc], bh.b, accN[t], 0, 0, 0);
        }
    }

    // ---- repack via per-wave LDS tiles (C layout: node=quad*4+r, j=16t+col)
    float* twE = tileE + wv * 576;
    float* twN = tileN + wv * 576;
#pragma unroll
    for (int t = 0; t < 2; t++) {
#pragma unroll
        for (int r = 0; r < 4; r++) {
            twE[(quad * 4 + r) * 36 + t * 16 + col] = accE[t][r];
            twN[(quad * 4 + r) * 36 + t * 16 + col] = accN[t][r];
        }
    }
    // Abf: lane -> (node=lane>>2, q=lane&3); 16B store, block-contiguous
    {
        int node = lane >> 2, q = lane & 3;
        const float* tr = twE + node * 36 + q * 8;
        uint4 v;
        v.x = f2bf_pair(tr[0], tr[1]); v.y = f2bf_pair(tr[2], tr[3]);
        v.z = f2bf_pair(tr[4], tr[5]); v.w = f2bf_pair(tr[6], tr[7]);
        if (nbase + node < N) Abf[(size_t)(nbase + node) * 4 + q] = v;
    }
    // A2: 128 float4s, coalesced
#pragma unroll
    for (int it = 0; it < 2; it++) {
        int fi = lane + it * 64;
        int node = fi >> 3, c = fi & 7;
        float4 fv = *(const float4*)(twN + node * 36 + c * 4);
        if (nbase + node < N)
            ((float4*)(A2 + (size_t)(nbase + node) * 32))[c] = fv;
    }
}

// ---------------------------------------------------------------------------
// Pass B: one block per bucket, 512 threads (8 waves). LDS deg/scan -> seg;
// cursor-scatter into dynamic LDS; ssrc written COALESCED.
// ---------------------------------------------------------------------------
extern __shared__ unsigned pls[];
__global__ __launch_bounds__(512) void k_bucketB(
    const unsigned* __restrict__ pairbuf, const int* __restrict__ gcnt,
    int2* __restrict__ seg, int* __restrict__ ssrc, int N, int C) {
    __shared__ int deg[256], scn[256], exc[256], cur[256];
    int b = blockIdx.x, tid = threadIdx.x;
    int cntb = gcnt[b];
    cntb = (cntb < C) ? cntb : C;
    if (tid < 256) { deg[tid] = 0; cur[tid] = 0; }
    __syncthreads();
    size_t basep = (size_t)b * C;
    for (int i = tid; i < cntb; i += 512)
        atomicAdd(&deg[pairbuf[basep + i] >> 20], 1);
    __syncthreads();
    if (tid < 256) scn[tid] = deg[tid];
    __syncthreads();
    for (int st = 1; st < 256; st <<= 1) {
        int add = (tid < 256 && tid >= st) ? scn[tid - st] : 0;
        __syncthreads();
        if (tid < 256) scn[tid] += add;
        __syncthreads();
    }
    if (tid < 256) {
        int ex = scn[tid] - deg[tid];
        exc[tid] = ex;
        int n = (b << BUCK_SHIFT) + tid;
        if (n < N) {
            int lo = b * C + ex;
            seg[n] = make_int2(lo, lo + deg[tid]);
        }
    }
    __syncthreads();
    for (int i = tid; i < cntb; i += 512) {
        unsigned p = pairbuf[basep + i];
        int l = (int)(p >> 20);
        int slot = exc[l] + atomicAdd(&cur[l], 1);
        pls[slot] = p & 0xFFFFFu;
    }
    __syncthreads();
    for (int i = tid; i < cntb; i += 512)
        ssrc[basep + i] = (int)pls[i];
}

// ---------------------------------------------------------------------------
// Fused edge-MLP + gather (EXACT R11/R2 verified 69.2us kernel).
// ---------------------------------------------------------------------------
__global__ __launch_bounds__(256) void fused_edge_gather(
    const int2* __restrict__ seg, const int* __restrict__ ssrc,
    const uint4* __restrict__ Abf, const float* __restrict__ posbuf,
    const float* __restrict__ Wf, const uint4* __restrict__ fragW2,
    float* __restrict__ sumh, int N, int npw) {
    int wid = blockIdx.x * 4 + (threadIdx.x >> 6);
    int lane = threadIdx.x & 63;
    int col = lane & 15, quad = lane >> 4;

    union { uint4 u; bf16x8 v; } cvt;
    bf16x8 bfr[4];
#pragma unroll
    for (int t = 0; t < 4; t++) {
        cvt.u = fragW2[t * 64 + lane];
        bfr[t] = cvt.v;
    }
    float c0[4];
#pragma unroll
    for (int t = 0; t < 4; t++) c0[t] = Wf[OFF_B2E + 16 * t + col];
    float wx[8], wy[8];
#pragma unroll
    for (int jj = 0; jj < 8; jj++) {
        float2 wv = ((const float2*)(Wf + OFF_W1POS))[quad * 8 + jj];
        wx[jj] = wv.x; wy[jj] = wv.y;
    }

    int n0 = wid * npw;
    int n1 = n0 + npw; n1 = (n1 < N) ? n1 : N;
#pragma unroll 1
    for (int n = n0; n < n1; n++) {
        int2 sg = seg[n];
        int lo = sg.x, hi = sg.y, deg = hi - lo;
        float2 pd = ((const float2*)posbuf)[n];
        float padd[8];
#pragma unroll
        for (int jj = 0; jj < 8; jj++)
            padd[jj] = fmaf(pd.x, wx[jj], pd.y * wy[jj]);

        float s0[4] = {0.f, 0.f, 0.f, 0.f};
        if (deg > 0) {
            int te = lo + col;
            te = (te < hi) ? te : (hi - 1);
            uint4 ar = Abf[(size_t)ssrc[te] * 4 + quad];
            int nfull = deg & ~15;
#pragma unroll 1
            for (int b = 0; b < nfull; b += 16) {
                // prefetch next batch (clamped; harmless re-read at the end)
                int teN = lo + b + 16 + col;
                teN = (teN < hi) ? teN : (hi - 1);
                uint4 arN = Abf[(size_t)ssrc[teN] * 4 + quad];

                bf16x8 af;
                {
                    float v0 = bf_lo(ar.x) + padd[0], v1 = bf_hi(ar.x) + padd[1];
                    float v2 = bf_lo(ar.y) + padd[2], v3 = bf_hi(ar.y) + padd[3];
                    float v4 = bf_lo(ar.z) + padd[4], v5 = bf_hi(ar.z) + padd[5];
                    float v6 = bf_lo(ar.w) + padd[6], v7 = bf_hi(ar.w) + padd[7];
                    v0 = fmaxf(v0, LRELU_SLOPE * v0); v1 = fmaxf(v1, LRELU_SLOPE * v1);
                    v2 = fmaxf(v2, LRELU_SLOPE * v2); v3 = fmaxf(v3, LRELU_SLOPE * v3);
                    v4 = fmaxf(v4, LRELU_SLOPE * v4); v5 = fmaxf(v5, LRELU_SLOPE * v5);
                    v6 = fmaxf(v6, LRELU_SLOPE * v6); v7 = fmaxf(v7, LRELU_SLOPE * v7);
                    af[0] = (__bf16)v0; af[1] = (__bf16)v1; af[2] = (__bf16)v2; af[3] = (__bf16)v3;
                    af[4] = (__bf16)v4; af[5] = (__bf16)v5; af[6] = (__bf16)v6; af[7] = (__bf16)v7;
                }
#pragma unroll
                for (int t = 0; t < 4; t++) {
                    f32x4 acc = {c0[t], c0[t], c0[t], c0[t]};
                    acc = __builtin_amdgcn_mfma_f32_16x16x32_bf16(af, bfr[t], acc, 0, 0, 0);
                    float u0 = __builtin_amdgcn_exp2f(acc[0]);
                    float u1 = __builtin_amdgcn_exp2f(acc[1]);
                    float u2 = __builtin_amdgcn_exp2f(acc[2]);
                    float u3 = __builtin_amdgcn_exp2f(acc[3]);
                    float q01 = u0 + u1, q23 = u2 + u3;
                    float d01 = fmaf(u0, u1, q01) + 1.f;
                    float d23 = fmaf(u2, u3, q23) + 1.f;
                    s0[t] = fmaf(q01 + 2.f, __builtin_amdgcn_rcpf(d01), s0[t]);
                    s0[t] = fmaf(q23 + 2.f, __builtin_amdgcn_rcpf(d23), s0[t]);
                }
                ar = arN;
            }
            int tail = deg - nfull;
            if (tail) {
                bf16x8 af;
                {
                    float v0 = bf_lo(ar.x) + padd[0], v1 = bf_hi(ar.x) + padd[1];
                    float v2 = bf_lo(ar.y) + padd[2], v3 = bf_hi(ar.y) + padd[3];
                    float v4 = bf_lo(ar.z) + padd[4], v5 = bf_hi(ar.z) + padd[5];
                    float v6 = bf_lo(ar.w) + padd[6], v7 = bf_hi(ar.w) + padd[7];
                    v0 = fmaxf(v0, LRELU_SLOPE * v0); v1 = fmaxf(v1, LRELU_SLOPE * v1);
                    v2 = fmaxf(v2, LRELU_SLOPE * v2); v3 = fmaxf(v3, LRELU_SLOPE * v3);
                    v4 = fmaxf(v4, LRELU_SLOPE * v4); v5 = fmaxf(v5, LRELU_SLOPE * v5);
                    v6 = fmaxf(v6, LRELU_SLOPE * v6); v7 = fmaxf(v7, LRELU_SLOPE * v7);
                    af[0] = (__bf16)v0; af[1] = (__bf16)v1; af[2] = (__bf16)v2; af[3] = (__bf16)v3;
                    af[4] = (__bf16)v4; af[5] = (__bf16)v5; af[6] = (__bf16)v6; af[7] = (__bf16)v7;
                }
                int rowb = quad * 4;
#pragma unroll
                for (int t = 0; t < 4; t++) {
                    f32x4 acc = {c0[t], c0[t], c0[t], c0[t]};
                    acc = __builtin_amdgcn_mfma_f32_16x16x32_bf16(af, bfr[t], acc, 0, 0, 0);
                    // invalid rows: u = 1e30 -> pair algebra makes the
                    // contribution ~2^-60 (drops out); double-invalid ~0.
                    float u0 = (rowb + 0 < tail) ? __builtin_amdgcn_exp2f(acc[0]) : 1e30f;
                    float u1 = (rowb + 1 < tail) ? __builtin_amdgcn_exp2f(acc[1]) : 1e30f;
                    float u2 = (rowb + 2 < tail) ? __builtin_amdgcn_exp2f(acc[2]) : 1e30f;
                    float u3 = (rowb + 3 < tail) ? __builtin_amdgcn_exp2f(acc[3]) : 1e30f;
                    float q01 = u0 + u1, q23 = u2 + u3;
                    float d01 = fmaf(u0, u1, q01) + 1.f;
                    float d23 = fmaf(u2, u3, q23) + 1.f;
                    s0[t] = fmaf(q01 + 2.f, __builtin_amdgcn_rcpf(d01), s0[t]);
                    s0[t] = fmaf(q23 + 2.f, __builtin_amdgcn_rcpf(d23), s0[t]);
                }
            }
        }
#pragma unroll
        for (int t = 0; t < 4; t++) {
            s0[t] += __shfl_xor(s0[t], 16);
            s0[t] += __shfl_xor(s0[t], 32);
        }
        if (lane < 16) {
            float* sr = sumh + (size_t)n * 64;
            float fd = (float)deg;
#pragma unroll
            for (int t = 0; t < 4; t++) sr[16 * t + lane] = fmaf(-2.f, s0[t], fd);
        }
    }
}

// ---------------------------------------------------------------------------
// Node MLP via MFMA: 16 nodes per wave (verified R19, ~19us).
// ---------------------------------------------------------------------------
__global__ __launch_bounds__(256) void k_node4(
    const float* __restrict__ A2, const float* __restrict__ sumh,
    const float* __restrict__ Wf, const uint4* __restrict__ frag1,
    const uint4* __restrict__ frag2, float* __restrict__ out,
    int N, int ngroups) {
    __shared__ float ylds[4 * 16 * 36];   // per-wave [16 nodes][32 y + pad4]
    int wv = threadIdx.x >> 6, lane = threadIdx.x & 63;
    int col = lane & 15, quad = lane >> 4;
    int g = blockIdx.x * 4 + wv;
    bool live = (g < ngroups);
    int gc = live ? g : (ngroups - 1);
    int nbase = gc * 16;

    // ---- S A-frags (hi/lo), 2 k-chunks: lane = (node=col, k=quad*8..+8) ----
    int nA = nbase + col; nA = (nA < N) ? nA : (N - 1);
    const float* srow = sumh + (size_t)nA * 64 + quad * 8;
    bf16x8 sh[2], sl[2];
#pragma unroll
    for (int kc = 0; kc < 2; kc++) {
        float4 f0 = *(const float4*)(srow + kc * 32);
        float4 f1 = *(const float4*)(srow + kc * 32 + 4);
        sh[kc] = pack8(f0.x, f0.y, f0.z, f0.w, f1.x, f1.y, f1.z, f1.w);
        sl[kc] = pack8(f0.x - bf_round(f0.x), f0.y - bf_round(f0.y),
                       f0.z - bf_round(f0.z), f0.w - bf_round(f0.w),
                       f1.x - bf_round(f1.x), f1.y - bf_round(f1.y),
                       f1.z - bf_round(f1.z), f1.w - bf_round(f1.w));
    }

    // ---- layer 1: acc1[t] = S x W1T (2 N-tiles) ----
    f32x4 acc1[2];
#pragma unroll
    for (int t = 0; t < 2; t++) { f32x4 z = {0.f, 0.f, 0.f, 0.f}; acc1[t] = z; }
#pragma unroll
    for (int kc = 0; kc < 2; kc++) {
#pragma unroll
        for (int t = 0; t < 2; t++) {
            union { uint4 u; bf16x8 b; } bh, bl;
            bh.u = frag1[((kc * 2 + t) * 2 + 0) * 64 + lane];
            bl.u = frag1[((kc * 2 + t) * 2 + 1) * 64 + lane];
            acc1[t] = __builtin_amdgcn_mfma_f32_16x16x32_bf16(sh[kc], bh.b, acc1[t], 0, 0, 0);
            acc1[t] = __builtin_amdgcn_mfma_f32_16x16x32_bf16(sh[kc], bl.b, acc1[t], 0, 0, 0);
            acc1[t] = __builtin_amdgcn_mfma_f32_16x16x32_bf16(sl[kc], bh.b, acc1[t], 0, 0, 0);
        }
    }

    // ---- +A2, lrelu, stash Y in LDS (C layout: node=quad*4+r, j=16t+col) ----
    float* yw = ylds + wv * 576;
#pragma unroll
    for (int t = 0; t < 2; t++) {
#pragma unroll
        for (int r = 0; r < 4; r++) {
            int ndr = quad * 4 + r;
            int nd = nbase + ndr; nd = (nd < N) ? nd : (N - 1);
            float yv = acc1[t][r] + A2[(size_t)nd * 32 + t * 16 + col];
            yv = fmaxf(yv, LRELU_SLOPE * yv);
            yw[ndr * 36 + t * 16 + col] = yv;
        }
    }
    __syncthreads();   // orders own-wave LDS writes -> reads (and block)

    // ---- Y A-frag (hi/lo): lane = (node=col, k=quad*8..+8) ----
    const float* yr = ylds + wv * 576 + col * 36 + quad * 8;
    float4 y0 = *(const float4*)(yr);
    float4 y1 = *(const float4*)(yr + 4);
    bf16x8 yh = pack8(y0.x, y0.y, y0.z, y0.w, y1.x, y1.y, y1.z, y1.w);
    bf16x8 yl = pack8(y0.x - bf_round(y0.x), y0.y - bf_round(y0.y),
                      y0.z - bf_round(y0.z), y0.w - bf_round(y0.w),
                      y1.x - bf_round(y1.x), y1.y - bf_round(y1.y),
                      y1.z - bf_round(y1.z), y1.w - bf_round(y1.w));

    // ---- layer 2: acc2[t] = Y x W2n + b2n (scaled); tanh; store ----
    f32x4 acc2[4];
#pragma unroll
    for (int t = 0; t < 4; t++) {
        float b = Wf[OFF_B2N + t * 16 + col] * TANH_SCALE;
        f32x4 z = {b, b, b, b}; acc2[t] = z;
    }
#pragma unroll
    for (int t = 0; t < 4; t++) {
        union { uint4 u; bf16x8 b; } bh, bl;
        bh.u = frag2[(t * 2 + 0) * 64 + lane];
        bl.u = frag2[(t * 2 + 1) * 64 + lane];
        acc2[t] = __builtin_amdgcn_mfma_f32_16x16x32_bf16(yh, bh.b, acc2[t], 0, 0, 0);
        acc2[t] = __builtin_amdgcn_mfma_f32_16x16x32_bf16(yh, bl.b, acc2[t], 0, 0, 0);
        acc2[t] = __builtin_amdgcn_mfma_f32_16x16x32_bf16(yl, bh.b, acc2[t], 0, 0, 0);
    }
    if (live) {
#pragma unroll
        for (int t = 0; t < 4; t++) {
#pragma unroll
            for (int r = 0; r < 4; r++) {
                int nd = nbase + quad * 4 + r;
                if (nd < N) {
                    float e = __builtin_amdgcn_exp2f(acc2[t][r]);
                    out[(size_t)nd * 64 + t * 16 + col] =
                        1.f - 2.f * __builtin_amdgcn_rcpf(e + 1.f);
                }
            }
        }
    }
}

// ---------------------------------------------------------------------------
extern "C" void kernel_launch(void* const* d_in, const int* in_sizes, int n_in,
                              void* d_out, int out_size, void* d_ws, size_t ws_size,
                              hipStream_t stream) {
    const float* hbuf   = (const float*)d_in[0];
    const float* ubuf   = (const float*)d_in[1];
    const float* posbuf = (const float*)d_in[2];
    const int* src = (const int*)d_in[3];
    const int* dst = (const int*)d_in[4];

    int N = in_sizes[0] / 64;
    int E = in_sizes[3];
    int NBUCK = (N + 255) >> BUCK_SHIFT;                 // 256-node buckets
    int C = ((2 * ((E + NBUCK - 1) / NBUCK)) + 255) & ~255;  // bucket capacity
    int nblkA = (E + 2047) / 2048;

    char* p = (char*)d_ws;
    auto alloc = [&](size_t bytes) {
        char* r = p;
        p += (bytes + 255) & ~(size_t)255;
        return r;
    };
    float*    Wf      = (float*)alloc(W_TOTAL * 4);
    uint4*    fragW2  = (uint4*)alloc(4 * 64 * 16);
    uint4*    frag1   = (uint4*)alloc(512 * 16);
    uint4*    frag2   = (uint4*)alloc(512 * 16);
    uint4*    fragE   = (uint4*)alloc(768 * 16);
    uint4*    fragN   = (uint4*)alloc(768 * 16);
    uint4*    Abf     = (uint4*)alloc((size_t)N * 64);   // bf16 A rows, 64B
    float*    A2      = (float*)alloc((size_t)N * 32 * 4);
    float*    sumh    = (float*)alloc((size_t)N * 64 * 4);
    int2*     seg     = (int2*)alloc((size_t)N * 8);
    int*      gcnt    = (int*)alloc((size_t)NBUCK * 4);
    unsigned* pairbuf = (unsigned*)alloc((size_t)NBUCK * C * 4);
    int*      ssrc    = (int*)alloc((size_t)NBUCK * C * 4);

    prep_weights<<<32, 256, 0, stream>>>(
        (const float*)d_in[5], (const float*)d_in[6],
        (const float*)d_in[7], (const float*)d_in[8],
        (const float*)d_in[9], (const float*)d_in[10],
        (const float*)d_in[11], (const float*)d_in[12], Wf, fragW2,
        frag1, frag2, fragE, fragN, gcnt, NBUCK);

    int ngroups = (N + 15) / 16;
    int nblkP = nblkA + (ngroups + 3) / 4;
    k_phase1<<<nblkP, 256, 0, stream>>>(
        hbuf, ubuf, posbuf, Wf, fragE, fragN, Abf, A2, src, dst,
        gcnt, pairbuf, E, N, C, nblkA);

    k_bucketB<<<NBUCK, 512, (size_t)C * 4, stream>>>(
        pairbuf, gcnt, seg, ssrc, N, C);

    const int FBLK = 2048;                    // 8192 waves = full machine
    int npw = (N + FBLK * 4 - 1) / (FBLK * 4);
    fused_edge_gather<<<FBLK, 256, 0, stream>>>(
        seg, ssrc, Abf, posbuf, Wf, fragW2, sumh, N, npw);

    k_node4<<<(ngroups + 3) / 4, 256, 0, stream>>>(
        A2, sumh, Wf, frag1, frag2, (float*)d_out, N, ngroups);
}

// Round 12
// 224.797 us; speedup vs baseline: 1.3689x; 1.0472x over previous
//
#include <hip/hip_runtime.h>

// ---------------------------------------------------------------------------
// GNN predictor (fp32 I/O). Round 21 = R20 (235.4us) with the bucket-sort
// path rebuilt ATOMIC-FREE and split into separate kernels for attribution:
//   k_sortA   (391 blk x 512t): block-local LDS counting sort of 4096 edges
//             -> blockbuf (coalesced bursts) + packoff[b][k]=(exc<<13|cnt).
//             ZERO global atomics (R20's gcnt storm: 782 blocks x 391
//             same-address device RMWs, serialized at the fabric).
//   k_bucketB2(391 blk x 512t): scan 391 run-lengths (LDS), gather runs
//             (scattered READS, no RMW), deg/scan -> seg, cursor-scatter
//             ssrc into block-private C-region (single-L2 full lines).
//   k_pre     : R20's MFMA precompute, own launch (visibility).
// R20 LESSON: per-block global reservation atomics to shared counters are
// serialized memory-side RMWs; doubling blocks doubled the storm.
// R19 LESSON: MFMA + preloaded frags + hi/lo bf16 3-term (k_node4 58->19us).
// R9/R8 LESSONS: threadIdx-derived weight addrs -> vector loads; __shfl/
// bpermute are LDS-pipe ops. R7: keep fused/node split (VGPR).
// R12/R13 (R4): per-edge device atomics = ~64B RMW each. R10: no global
// cursor. Fused VALU diet verified R11.
// ---------------------------------------------------------------------------

#define LRELU_SLOPE 0.01f
#define BUCK_SHIFT 8                  // 256 nodes per bucket
#define TANH_SCALE 2.8853900817779268f  // 2*log2(e)
#define EPB 4096                      // edges per sort block

constexpr int OFF_B1E   = 2432;       // [32]
constexpr int OFF_B2E   = 4512;       // [64]      pre-scaled by TANH_SCALE
constexpr int OFF_B2N   = 11104;      // [64]
constexpr int OFF_B1N   = 11168;      // [32]
constexpr int OFF_W1POS = 11200;      // [32] float2 (W1e rows 2,3)
constexpr int W_TOTAL   = 11264;

typedef __bf16 bf16x8 __attribute__((ext_vector_type(8)));
typedef float  f32x4  __attribute__((ext_vector_type(4)));

__device__ __forceinline__ unsigned f2bf_pair(float f0, float f1) {
    unsigned u0 = __float_as_uint(f0), u1 = __float_as_uint(f1);
    unsigned r0 = (u0 + 0x7fffu + ((u0 >> 16) & 1u)) >> 16;   // RNE
    unsigned r1 = (u1 + 0x7fffu + ((u1 >> 16) & 1u)) >> 16;
    return r0 | (r1 << 16);
}
__device__ __forceinline__ float bf_lo(unsigned p) { return __uint_as_float(p << 16); }
__device__ __forceinline__ float bf_hi(unsigned p) { return __uint_as_float(p & 0xffff0000u); }
__device__ __forceinline__ float bf_round(float f) {  // f32 value of RNE bf16(f)
    unsigned u = __float_as_uint(f);
    return __uint_as_float((u + 0x7fffu + ((u >> 16) & 1u)) & 0xffff0000u);
}
__device__ __forceinline__ bf16x8 pack8(float a0, float a1, float a2, float a3,
                                        float a4, float a5, float a6, float a7) {
    union { uint4 u; bf16x8 b; } c;
    c.u.x = f2bf_pair(a0, a1); c.u.y = f2bf_pair(a2, a3);
    c.u.z = f2bf_pair(a4, a5); c.u.w = f2bf_pair(a6, a7);
    return c.b;
}

// X96 row maps: X = [h(64) | pos.x,pos.y,0,0,u(8),0*20]
__device__ __forceinline__ float w1e_x96(const float* W1e, int i, int j) {
    if (i < 64) return W1e[(12 + i) * 32 + j];
    if (i == 64) return W1e[0 * 32 + j];
    if (i == 65) return W1e[1 * 32 + j];
    if (i >= 68 && i < 76) return W1e[(4 + i - 68) * 32 + j];
    return 0.f;
}
__device__ __forceinline__ float w1n_x96(const float* W1n, int i, int j) {
    if (i < 64) return W1n[(2 + i) * 32 + j];
    if (i == 64) return W1n[0 * 32 + j];
    if (i == 65) return W1n[1 * 32 + j];
    if (i >= 68 && i < 76) return W1n[(130 + i - 68) * 32 + j];
    return 0.f;
}

// ---------------------------------------------------------------------------
__global__ void prep_weights(const float* __restrict__ W1e, const float* __restrict__ b1e,
                             const float* __restrict__ W2e, const float* __restrict__ b2e,
                             const float* __restrict__ W1n, const float* __restrict__ b1n,
                             const float* __restrict__ W2n, const float* __restrict__ b2n,
                             float* __restrict__ Wf, uint4* __restrict__ fragW2,
                             uint4* __restrict__ frag1, uint4* __restrict__ frag2,
                             uint4* __restrict__ fragE, uint4* __restrict__ fragN) {
    int t = blockIdx.x * blockDim.x + threadIdx.x;
    int T = gridDim.x * blockDim.x;
    for (int idx = t; idx < 32; idx += T)   Wf[OFF_B1E + idx] = b1e[idx];
    for (int idx = t; idx < 64; idx += T)   Wf[OFF_B2E + idx] = b2e[idx] * TANH_SCALE;
    for (int idx = t; idx < 64; idx += T)   Wf[OFF_B2N + idx] = b2n[idx];
    for (int idx = t; idx < 32; idx += T)   Wf[OFF_B1N + idx] = b1n[idx];
    for (int idx = t; idx < 32; idx += T) {
        Wf[OFF_W1POS + 2 * idx + 0] = W1e[2 * 32 + idx];
        Wf[OFF_W1POS + 2 * idx + 1] = W1e[3 * 32 + idx];
    }
    // MFMA B-fragments for W2e (bf16, pre-scaled), 4 N-tiles x 64 lanes x 16B
    for (int idx = t; idx < 256; idx += T) {
        int tt = idx >> 6, l = idx & 63;
        int colv = l & 15, quadv = l >> 4;
        uint4 v;
        unsigned pk[4];
#pragma unroll
        for (int pr = 0; pr < 4; pr++) {
            int j0 = quadv * 8 + 2 * pr;
            float f0 = W2e[j0 * 64 + 16 * tt + colv] * TANH_SCALE;
            float f1 = W2e[(j0 + 1) * 64 + 16 * tt + colv] * TANH_SCALE;
            pk[pr] = f2bf_pair(f0, f1);
        }
        v.x = pk[0]; v.y = pk[1]; v.z = pk[2]; v.w = pk[3];
        fragW2[tt * 64 + l] = v;
    }
    // node layer-1 B-frags (sumh part): B[i][j] = W1n[(66+i)*32+j], hi/lo
    for (int idx = t; idx < 512; idx += T) {
        int l = idx & 63, rest = idx >> 6;
        int hl = rest & 1, tt = (rest >> 1) & 1, kc = rest >> 2;
        int colv = l & 15, quadv = l >> 4;
        unsigned pk[4];
#pragma unroll
        for (int pr = 0; pr < 4; pr++) {
            int i0 = kc * 32 + quadv * 8 + 2 * pr;
            float f0 = W1n[(66 + i0) * 32 + tt * 16 + colv];
            float f1 = W1n[(66 + i0 + 1) * 32 + tt * 16 + colv];
            if (hl) { f0 -= bf_round(f0); f1 -= bf_round(f1); }
            pk[pr] = f2bf_pair(f0, f1);
        }
        uint4 v; v.x = pk[0]; v.y = pk[1]; v.z = pk[2]; v.w = pk[3];
        frag1[idx] = v;
    }
    // node layer-2 B-frags: B[j][k] = W2n[j*64+k]*TANH_SCALE, hi/lo
    for (int idx = t; idx < 512; idx += T) {
        int l = idx & 63, rest = idx >> 6;
        int hl = rest & 1, tt = rest >> 1;
        int colv = l & 15, quadv = l >> 4;
        unsigned pk[4];
#pragma unroll
        for (int pr = 0; pr < 4; pr++) {
            int j0 = quadv * 8 + 2 * pr;
            float f0 = W2n[j0 * 64 + tt * 16 + colv] * TANH_SCALE;
            float f1 = W2n[(j0 + 1) * 64 + tt * 16 + colv] * TANH_SCALE;
            if (hl) { f0 -= bf_round(f0); f1 -= bf_round(f1); }
            pk[pr] = f2bf_pair(f0, f1);
        }
        uint4 v; v.x = pk[0]; v.y = pk[1]; v.z = pk[2]; v.w = pk[3];
        frag2[idx] = v;
    }
    // phase1 precompute B-frags over X96: fragE / fragN, [kc(3)][tt(2)][hl(2)][64]
    for (int idx = t; idx < 768; idx += T) {
        int l = idx & 63, rest = idx >> 6;
        int hl = rest & 1, tt = (rest >> 1) & 1, kc = rest >> 2;
        int colv = l & 15, quadv = l >> 4;
        int j = tt * 16 + colv;
        unsigned pkE[4], pkN[4];
#pragma unroll
        for (int pr = 0; pr < 4; pr++) {
            int i0 = kc * 32 + quadv * 8 + 2 * pr;
            float e0 = w1e_x96(W1e, i0, j), e1 = w1e_x96(W1e, i0 + 1, j);
            float n0 = w1n_x96(W1n, i0, j), n1 = w1n_x96(W1n, i0 + 1, j);
            if (hl) {
                e0 -= bf_round(e0); e1 -= bf_round(e1);
                n0 -= bf_round(n0); n1 -= bf_round(n1);
            }
            pkE[pr] = f2bf_pair(e0, e1);
            pkN[pr] = f2bf_pair(n0, n1);
        }
        uint4 ve; ve.x = pkE[0]; ve.y = pkE[1]; ve.z = pkE[2]; ve.w = pkE[3];
        uint4 vn; vn.x = pkN[0]; vn.y = pkN[1]; vn.z = pkN[2]; vn.w = pkN[3];
        fragE[idx] = ve;
        fragN[idx] = vn;
    }
}

// ---------------------------------------------------------------------------
// MFMA per-node precompute: 16 nodes per wave (R20 code, own kernel).
//   Abf[n][32] bf16 : edge-MLP layer1 src part
//   A2 [n][32] f32  : node-MLP layer1 pos/h/u part (+b1n)
// ---------------------------------------------------------------------------
__global__ __launch_bounds__(256) void k_pre(
    const float* __restrict__ hbuf, const float* __restrict__ ubuf,
    const float* __restrict__ posbuf, const float* __restrict__ Wf,
    const uint4* __restrict__ fragE, const uint4* __restrict__ fragN,
    uint4* __restrict__ Abf, float* __restrict__ A2, int N) {
    __shared__ float tileE[4 * 16 * 36], tileN[4 * 16 * 36];
    int tid = threadIdx.x;
    int wv = tid >> 6, lane = tid & 63;
    int col = lane & 15, quad = lane >> 4;
    int g = (int)blockIdx.x * 4 + wv;
    int ngroups = (N + 15) >> 4;
    if (g >= ngroups) return;
    int nbase = g * 16;
    int nA = nbase + col; nA = (nA < N) ? nA : (N - 1);

    bf16x8 xh[3], xl[3];
    {
        const float* hrow = hbuf + (size_t)nA * 64 + quad * 8;
        float4 f0 = *(const float4*)(hrow);
        float4 f1 = *(const float4*)(hrow + 4);
        xh[0] = pack8(f0.x, f0.y, f0.z, f0.w, f1.x, f1.y, f1.z, f1.w);
        xl[0] = pack8(f0.x - bf_round(f0.x), f0.y - bf_round(f0.y),
                      f0.z - bf_round(f0.z), f0.w - bf_round(f0.w),
                      f1.x - bf_round(f1.x), f1.y - bf_round(f1.y),
                      f1.z - bf_round(f1.z), f1.w - bf_round(f1.w));
        float4 g0 = *(const float4*)(hrow + 32);
        float4 g1 = *(const float4*)(hrow + 36);
        xh[1] = pack8(g0.x, g0.y, g0.z, g0.w, g1.x, g1.y, g1.z, g1.w);
        xl[1] = pack8(g0.x - bf_round(g0.x), g0.y - bf_round(g0.y),
                      g0.z - bf_round(g0.z), g0.w - bf_round(g0.w),
                      g1.x - bf_round(g1.x), g1.y - bf_round(g1.y),
                      g1.z - bf_round(g1.z), g1.w - bf_round(g1.w));
    }
    {
        float xv[8];
#pragma unroll
        for (int i = 0; i < 8; i++) xv[i] = 0.f;
        if (quad == 0) {
            float2 pp = ((const float2*)posbuf)[nA];
            float4 uu = ((const float4*)ubuf)[(size_t)nA * 2];
            xv[0] = pp.x; xv[1] = pp.y;
            xv[4] = uu.x; xv[5] = uu.y; xv[6] = uu.z; xv[7] = uu.w;
        } else if (quad == 1) {
            float4 ub = ((const float4*)ubuf)[(size_t)nA * 2 + 1];
            xv[0] = ub.x; xv[1] = ub.y; xv[2] = ub.z; xv[3] = ub.w;
        }
        xh[2] = pack8(xv[0], xv[1], xv[2], xv[3], xv[4], xv[5], xv[6], xv[7]);
        xl[2] = pack8(xv[0] - bf_round(xv[0]), xv[1] - bf_round(xv[1]),
                      xv[2] - bf_round(xv[2]), xv[3] - bf_round(xv[3]),
                      xv[4] - bf_round(xv[4]), xv[5] - bf_round(xv[5]),
                      xv[6] - bf_round(xv[6]), xv[7] - bf_round(xv[7]));
    }

    f32x4 accE[2], accN[2];
#pragma unroll
    for (int t = 0; t < 2; t++) {
        float be = Wf[OFF_B1E + t * 16 + col];
        float bn = Wf[OFF_B1N + t * 16 + col];
        f32x4 e = {be, be, be, be}; accE[t] = e;
        f32x4 n = {bn, bn, bn, bn}; accN[t] = n;
    }
#pragma unroll
    for (int kc = 0; kc < 3; kc++) {
#pragma unroll
        for (int t = 0; t < 2; t++) {
            union { uint4 u; bf16x8 b; } bh, bl;
            int fi = ((kc * 2 + t) * 2) * 64 + lane;
            bh.u = fragE[fi]; bl.u = fragE[fi + 64];
            accE[t] = __builtin_amdgcn_mfma_f32_16x16x32_bf16(xh[kc], bh.b, accE[t], 0, 0, 0);
            accE[t] = __builtin_amdgcn_mfma_f32_16x16x32_bf16(xh[kc], bl.b, accE[t], 0, 0, 0);
            accE[t] = __builtin_amdgcn_mfma_f32_16x16x32_bf16(xl[kc], bh.b, accE[t], 0, 0, 0);
            bh.u = fragN[fi]; bl.u = fragN[fi + 64];
            accN[t] = __builtin_amdgcn_mfma_f32_16x16x32_bf16(xh[kc], bh.b, accN[t], 0, 0, 0);
            accN[t] = __builtin_amdgcn_mfma_f32_16x16x32_bf16(xh[kc], bl.b, accN[t], 0, 0, 0);
            accN[t] = __builtin_amdgcn_mfma_f32_16x16x32_bf16(xl[kc], bh.b, accN[t], 0, 0, 0);
        }
    }

    float* twE = tileE + wv * 576;
    float* twN = tileN + wv * 576;
#pragma unroll
    for (int t = 0; t < 2; t++) {
#pragma unroll
        for (int r = 0; r < 4; r++) {
            twE[(quad * 4 + r) * 36 + t * 16 + col] = accE[t][r];
            twN[(quad * 4 + r) * 36 + t * 16 + col] = accN[t][r];
        }
    }
    __syncthreads();
    {
        int node = lane >> 2, q = lane & 3;
        const float* tr = twE + node * 36 + q * 8;
        uint4 v;
        v.x = f2bf_pair(tr[0], tr[1]); v.y = f2bf_pair(tr[2], tr[3]);
        v.z = f2bf_pair(tr[4], tr[5]); v.w = f2bf_pair(tr[6], tr[7]);
        if (nbase + node < N) Abf[(size_t)(nbase + node) * 4 + q] = v;
    }
#pragma unroll
    for (int it = 0; it < 2; it++) {
        int fi = lane + it * 64;
        int node = fi >> 3, c = fi & 7;
        float4 fv = *(const float4*)(twN + node * 36 + c * 4);
        if (nbase + node < N)
            ((float4*)(A2 + (size_t)(nbase + node) * 32))[c] = fv;
    }
}

// ---------------------------------------------------------------------------
// k_sortA: block-local counting sort of EPB edges. No global atomics.
// Outputs: blockbuf[k*EPB + i] sorted pairs (src | dnode<<20), coalesced;
//          packoff[b*512 + k] = (exc<<13) | cnt   (exc,cnt <= 4096).
// ---------------------------------------------------------------------------
__global__ __launch_bounds__(512) void k_sortA(
    const int* __restrict__ src, const int* __restrict__ dst,
    unsigned* __restrict__ blockbuf, unsigned* __restrict__ packoff, int E) {
    __shared__ int cnt[512], scn[512], exc[512], cur[512];
    __shared__ unsigned sorted[EPB];
    int k = blockIdx.x, tid = threadIdx.x;
    int e0 = k * EPB;
    cnt[tid] = 0; cur[tid] = 0;
    __syncthreads();
    int bs[8]; unsigned pv[8];
#pragma unroll
    for (int j = 0; j < 8; j++) {
        int e = e0 + j * 512 + tid;
        if (e < E) {
            int d = dst[e];
            bs[j] = d >> BUCK_SHIFT;
            pv[j] = (unsigned)src[e] | ((unsigned)(d & 255) << 20);
            atomicAdd(&cnt[bs[j]], 1);
        } else bs[j] = -1;
    }
    __syncthreads();
    scn[tid] = cnt[tid];
    __syncthreads();
    for (int st = 1; st < 512; st <<= 1) {
        int add = (tid >= st) ? scn[tid - st] : 0;
        __syncthreads();
        scn[tid] += add;
        __syncthreads();
    }
    int ex = scn[tid] - cnt[tid];
    exc[tid] = ex;
    packoff[(size_t)tid * 512 + k] = ((unsigned)ex << 13) | (unsigned)cnt[tid];
    __syncthreads();
    int tot = scn[511];
#pragma unroll
    for (int j = 0; j < 8; j++) {
        if (bs[j] >= 0) {
            int slot = exc[bs[j]] + atomicAdd(&cur[bs[j]], 1);
            sorted[slot] = pv[j];
        }
    }
    __syncthreads();
#pragma unroll
    for (int j = 0; j < 8; j++) {
        int i = j * 512 + tid;
        if (i < tot) blockbuf[(size_t)k * EPB + i] = sorted[i];
    }
}

// ---------------------------------------------------------------------------
// k_bucketB2: per bucket, scan run lengths over sort-blocks, gather runs
// into LDS (scattered reads), deg/scan -> seg, cursor-scatter ssrc into
// the bucket's private C-region.
// ---------------------------------------------------------------------------
extern __shared__ unsigned gath[];
__global__ __launch_bounds__(512) void k_bucketB2(
    const unsigned* __restrict__ blockbuf, const unsigned* __restrict__ packoff,
    int2* __restrict__ seg, int* __restrict__ ssrc, int N, int C, int nsort) {
    __shared__ int runc[512];
    __shared__ int deg[256], scn[256], exc[256], cur[256];
    int b = blockIdx.x, tid = threadIdx.x;
    unsigned po = packoff[(size_t)b * 512 + tid];
    int rcnt = (tid < nsort) ? (int)(po & 0x1FFFu) : 0;
    int rexc = (int)(po >> 13);
    runc[tid] = rcnt;
    __syncthreads();
    for (int st = 1; st < 512; st <<= 1) {
        int add = (tid >= st) ? runc[tid - st] : 0;
        __syncthreads();
        runc[tid] += add;
        __syncthreads();
    }
    int my0 = runc[tid] - rcnt;
    int cntb = runc[511];
    cntb = (cntb < C) ? cntb : C;
    if (tid < nsort && rcnt > 0) {
        const unsigned* rb = blockbuf + (size_t)tid * EPB + rexc;
        for (int i = 0; i < rcnt; i++) {
            int o = my0 + i;
            if (o < C) gath[o] = rb[i];
        }
    }
    if (tid < 256) { deg[tid] = 0; cur[tid] = 0; }
    __syncthreads();
    for (int i = tid; i < cntb; i += 512)
        atomicAdd(&deg[gath[i] >> 20], 1);
    __syncthreads();
    if (tid < 256) scn[tid] = deg[tid];
    __syncthreads();
    for (int st = 1; st < 256; st <<= 1) {
        int add = (tid < 256 && tid >= st) ? scn[tid - st] : 0;
        __syncthreads();
        if (tid < 256) scn[tid] += add;
        __syncthreads();
    }
    if (tid < 256) {
        int ex2 = scn[tid] - deg[tid];
        exc[tid] = ex2;
        int n = (b << BUCK_SHIFT) + tid;
        if (n < N) {
            int lo = b * C + ex2;
            seg[n] = make_int2(lo, lo + deg[tid]);
        }
    }
    __syncthreads();
    size_t basep = (size_t)b * C;
    for (int i = tid; i < cntb; i += 512) {
        unsigned p = gath[i];
        int l = (int)(p >> 20);
        int slot = exc[l] + atomicAdd(&cur[l], 1);
        ssrc[basep + slot] = (int)(p & 0xFFFFFu);
    }
}

// ---------------------------------------------------------------------------
// Fused edge-MLP + gather (EXACT R11/R2 verified 69.2us kernel).
// ---------------------------------------------------------------------------
__global__ __launch_bounds__(256) void fused_edge_gather(
    const int2* __restrict__ seg, const int* __restrict__ ssrc,
    const uint4* __restrict__ Abf, const float* __restrict__ posbuf,
    const float* __restrict__ Wf, const uint4* __restrict__ fragW2,
    float* __restrict__ sumh, int N, int npw) {
    int wid = blockIdx.x * 4 + (threadIdx.x >> 6);
    int lane = threadIdx.x & 63;
    int col = lane & 15, quad = lane >> 4;

    union { uint4 u; bf16x8 v; } cvt;
    bf16x8 bfr[4];
#pragma unroll
    for (int t = 0; t < 4; t++) {
        cvt.u = fragW2[t * 64 + lane];
        bfr[t] = cvt.v;
    }
    float c0[4];
#pragma unroll
    for (int t = 0; t < 4; t++) c0[t] = Wf[OFF_B2E + 16 * t + col];
    float wx[8], wy[8];
#pragma unroll
    for (int jj = 0; jj < 8; jj++) {
        float2 wv = ((const float2*)(Wf + OFF_W1POS))[quad * 8 + jj];
        wx[jj] = wv.x; wy[jj] = wv.y;
    }

    int n0 = wid * npw;
    int n1 = n0 + npw; n1 = (n1 < N) ? n1 : N;
#pragma unroll 1
    for (int n = n0; n < n1; n++) {
        int2 sg = seg[n];
        int lo = sg.x, hi = sg.y, deg = hi - lo;
        float2 pd = ((const float2*)posbuf)[n];
        float padd[8];
#pragma unroll
        for (int jj = 0; jj < 8; jj++)
            padd[jj] = fmaf(pd.x, wx[jj], pd.y * wy[jj]);

        float s0[4] = {0.f, 0.f, 0.f, 0.f};
        if (deg > 0) {
            int te = lo + col;
            te = (te < hi) ? te : (hi - 1);
            uint4 ar = Abf[(size_t)ssrc[te] * 4 + quad];
            int nfull = deg & ~15;
#pragma unroll 1
            for (int b = 0; b < nfull; b += 16) {
                // prefetch next batch (clamped; harmless re-read at the end)
                int teN = lo + b + 16 + col;
                teN = (teN < hi) ? teN : (hi - 1);
                uint4 arN = Abf[(size_t)ssrc[teN] * 4 + quad];

                bf16x8 af;
                {
                    float v0 = bf_lo(ar.x) + padd[0], v1 = bf_hi(ar.x) + padd[1];
                    float v2 = bf_lo(ar.y) + padd[2], v3 = bf_hi(ar.y) + padd[3];
                    float v4 = bf_lo(ar.z) + padd[4], v5 = bf_hi(ar.z) + padd[5];
                    float v6 = bf_lo(ar.w) + padd[6], v7 = bf_hi(ar.w) + padd[7];
                    v0 = fmaxf(v0, LRELU_SLOPE * v0); v1 = fmaxf(v1, LRELU_SLOPE * v1);
                    v2 = fmaxf(v2, LRELU_SLOPE * v2); v3 = fmaxf(v3, LRELU_SLOPE * v3);
                    v4 = fmaxf(v4, LRELU_SLOPE * v4); v5 = fmaxf(v5, LRELU_SLOPE * v5);
                    v6 = fmaxf(v6, LRELU_SLOPE * v6); v7 = fmaxf(v7, LRELU_SLOPE * v7);
                    af[0] = (__bf16)v0; af[1] = (__bf16)v1; af[2] = (__bf16)v2; af[3] = (__bf16)v3;
                    af[4] = (__bf16)v4; af[5] = (__bf16)v5; af[6] = (__bf16)v6; af[7] = (__bf16)v7;
                }
#pragma unroll
                for (int t = 0; t < 4; t++) {
                    f32x4 acc = {c0[t], c0[t], c0[t], c0[t]};
                    acc = __builtin_amdgcn_mfma_f32_16x16x32_bf16(af, bfr[t], acc, 0, 0, 0);
                    float u0 = __builtin_amdgcn_exp2f(acc[0]);
                    float u1 = __builtin_amdgcn_exp2f(acc[1]);
                    float u2 = __builtin_amdgcn_exp2f(acc[2]);
                    float u3 = __builtin_amdgcn_exp2f(acc[3]);
                    float q01 = u0 + u1, q23 = u2 + u3;
                    float d01 = fmaf(u0, u1, q01) + 1.f;
                    float d23 = fmaf(u2, u3, q23) + 1.f;
                    s0[t] = fmaf(q01 + 2.f, __builtin_amdgcn_rcpf(d01), s0[t]);
                    s0[t] = fmaf(q23 + 2.f, __builtin_amdgcn_rcpf(d23), s0[t]);
                }
                ar = arN;
            }
            int tail = deg - nfull;
            if (tail) {
                bf16x8 af;
                {
                    float v0 = bf_lo(ar.x) + padd[0], v1 = bf_hi(ar.x) + padd[1];
                    float v2 = bf_lo(ar.y) + padd[2], v3 = bf_hi(ar.y) + padd[3];
                    float v4 = bf_lo(ar.z) + padd[4], v5 = bf_hi(ar.z) + padd[5];
                    float v6 = bf_lo(ar.w) + padd[6], v7 = bf_hi(ar.w) + padd[7];
                    v0 = fmaxf(v0, LRELU_SLOPE * v0); v1 = fmaxf(v1, LRELU_SLOPE * v1);
                    v2 = fmaxf(v2, LRELU_SLOPE * v2); v3 = fmaxf(v3, LRELU_SLOPE * v3);
                    v4 = fmaxf(v4, LRELU_SLOPE * v4); v5 = fmaxf(v5, LRELU_SLOPE * v5);
                    v6 = fmaxf(v6, LRELU_SLOPE * v6); v7 = fmaxf(v7, LRELU_SLOPE * v7);
                    af[0] = (__bf16)v0; af[1] = (__bf16)v1; af[2] = (__bf16)v2; af[3] = (__bf16)v3;
                    af[4] = (__bf16)v4; af[5] = (__bf16)v5; af[6] = (__bf16)v6; af[7] = (__bf16)v7;
                }
                int rowb = quad * 4;
#pragma unroll
                for (int t = 0; t < 4; t++) {
                    f32x4 acc = {c0[t], c0[t], c0[t], c0[t]};
                    acc = __builtin_amdgcn_mfma_f32_16x16x32_bf16(af, bfr[t], acc, 0, 0, 0);
                    // invalid rows: u = 1e30 -> pair algebra makes the
                    // contribution ~2^-60 (drops out); double-invalid ~0.
                    float u0 = (rowb + 0 < tail) ? __builtin_amdgcn_exp2f(acc[0]) : 1e30f;
                    float u1 = (rowb + 1 < tail) ? __builtin_amdgcn_exp2f(acc[1]) : 1e30f;
                    float u2 = (rowb + 2 < tail) ? __builtin_amdgcn_exp2f(acc[2]) : 1e30f;
                    float u3 = (rowb + 3 < tail) ? __builtin_amdgcn_exp2f(acc[3]) : 1e30f;
                    float q01 = u0 + u1, q23 = u2 + u3;
                    float d01 = fmaf(u0, u1, q01) + 1.f;
                    float d23 = fmaf(u2, u3, q23) + 1.f;
                    s0[t] = fmaf(q01 + 2.f, __builtin_amdgcn_rcpf(d01), s0[t]);
                    s0[t] = fmaf(q23 + 2.f, __builtin_amdgcn_rcpf(d23), s0[t]);
                }
            }
        }
#pragma unroll
        for (int t = 0; t < 4; t++) {
            s0[t] += __shfl_xor(s0[t], 16);
            s0[t] += __shfl_xor(s0[t], 32);
        }
        if (lane < 16) {
            float* sr = sumh + (size_t)n * 64;
            float fd = (float)deg;
#pragma unroll
            for (int t = 0; t < 4; t++) sr[16 * t + lane] = fmaf(-2.f, s0[t], fd);
        }
    }
}

// ---------------------------------------------------------------------------
// Node MLP via MFMA: 16 nodes per wave (verified R19, ~19us).
// ---------------------------------------------------------------------------
__global__ __launch_bounds__(256) void k_node4(
    const float* __restrict__ A2, const float* __restrict__ sumh,
    const float* __restrict__ Wf, const uint4* __restrict__ frag1,
    const uint4* __restrict__ frag2, float* __restrict__ out,
    int N, int ngroups) {
    __shared__ float ylds[4 * 16 * 36];   // per-wave [16 nodes][32 y + pad4]
    int wv = threadIdx.x >> 6, lane = threadIdx.x & 63;
    int col = lane & 15, quad = lane >> 4;
    int g = blockIdx.x * 4 + wv;
    bool live = (g < ngroups);
    int gc = live ? g : (ngroups - 1);
    int nbase = gc * 16;

    int nA = nbase + col; nA = (nA < N) ? nA : (N - 1);
    const float* srow = sumh + (size_t)nA * 64 + quad * 8;
    bf16x8 sh[2], sl[2];
#pragma unroll
    for (int kc = 0; kc < 2; kc++) {
        float4 f0 = *(const float4*)(srow + kc * 32);
        float4 f1 = *(const float4*)(srow + kc * 32 + 4);
        sh[kc] = pack8(f0.x, f0.y, f0.z, f0.w, f1.x, f1.y, f1.z, f1.w);
        sl[kc] = pack8(f0.x - bf_round(f0.x), f0.y - bf_round(f0.y),
                       f0.z - bf_round(f0.z), f0.w - bf_round(f0.w),
                       f1.x - bf_round(f1.x), f1.y - bf_round(f1.y),
                       f1.z - bf_round(f1.z), f1.w - bf_round(f1.w));
    }

    f32x4 acc1[2];
#pragma unroll
    for (int t = 0; t < 2; t++) { f32x4 z = {0.f, 0.f, 0.f, 0.f}; acc1[t] = z; }
#pragma unroll
    for (int kc = 0; kc < 2; kc++) {
#pragma unroll
        for (int t = 0; t < 2; t++) {
            union { uint4 u; bf16x8 b; } bh, bl;
            bh.u = frag1[((kc * 2 + t) * 2 + 0) * 64 + lane];
            bl.u = frag1[((kc * 2 + t) * 2 + 1) * 64 + lane];
            acc1[t] = __builtin_amdgcn_mfma_f32_16x16x32_bf16(sh[kc], bh.b, acc1[t], 0, 0, 0);
            acc1[t] = __builtin_amdgcn_mfma_f32_16x16x32_bf16(sh[kc], bl.b, acc1[t], 0, 0, 0);
            acc1[t] = __builtin_amdgcn_mfma_f32_16x16x32_bf16(sl[kc], bh.b, acc1[t], 0, 0, 0);
        }
    }

    float* yw = ylds + wv * 576;
#pragma unroll
    for (int t = 0; t < 2; t++) {
#pragma unroll
        for (int r = 0; r < 4; r++) {
            int ndr = quad * 4 + r;
            int nd = nbase + ndr; nd = (nd < N) ? nd : (N - 1);
            float yv = acc1[t][r] + A2[(size_t)nd * 32 + t * 16 + col];
            yv = fmaxf(yv, LRELU_SLOPE * yv);
            yw[ndr * 36 + t * 16 + col] = yv;
        }
    }
    __syncthreads();

    const float* yr = ylds + wv * 576 + col * 36 + quad * 8;
    float4 y0 = *(const float4*)(yr);
    float4 y1 = *(const float4*)(yr + 4);
    bf16x8 yh = pack8(y0.x, y0.y, y0.z, y0.w, y1.x, y1.y, y1.z, y1.w);
    bf16x8 yl = pack8(y0.x - bf_round(y0.x), y0.y - bf_round(y0.y),
                      y0.z - bf_round(y0.z), y0.w - bf_round(y0.w),
                      y1.x - bf_round(y1.x), y1.y - bf_round(y1.y),
                      y1.z - bf_round(y1.z), y1.w - bf_round(y1.w));

    f32x4 acc2[4];
#pragma unroll
    for (int t = 0; t < 4; t++) {
        float b = Wf[OFF_B2N + t * 16 + col] * TANH_SCALE;
        f32x4 z = {b, b, b, b}; acc2[t] = z;
    }
#pragma unroll
    for (int t = 0; t < 4; t++) {
        union { uint4 u; bf16x8 b; } bh, bl;
        bh.u = frag2[(t * 2 + 0) * 64 + lane];
        bl.u = frag2[(t * 2 + 1) * 64 + lane];
        acc2[t] = __builtin_amdgcn_mfma_f32_16x16x32_bf16(yh, bh.b, acc2[t], 0, 0, 0);
        acc2[t] = __builtin_amdgcn_mfma_f32_16x16x32_bf16(yh, bl.b, acc2[t], 0, 0, 0);
        acc2[t] = __builtin_amdgcn_mfma_f32_16x16x32_bf16(yl, bh.b, acc2[t], 0, 0, 0);
    }
    if (live) {
#pragma unroll
        for (int t = 0; t < 4; t++) {
#pragma unroll
            for (int r = 0; r < 4; r++) {
                int nd = nbase + quad * 4 + r;
                if (nd < N) {
                    float e = __builtin_amdgcn_exp2f(acc2[t][r]);
                    out[(size_t)nd * 64 + t * 16 + col] =
                        1.f - 2.f * __builtin_amdgcn_rcpf(e + 1.f);
                }
            }
        }
    }
}

// ---------------------------------------------------------------------------
extern "C" void kernel_launch(void* const* d_in, const int* in_sizes, int n_in,
                              void* d_out, int out_size, void* d_ws, size_t ws_size,
                              hipStream_t stream) {
    const float* hbuf   = (const float*)d_in[0];
    const float* ubuf   = (const float*)d_in[1];
    const float* posbuf = (const float*)d_in[2];
    const int* src = (const int*)d_in[3];
    const int* dst = (const int*)d_in[4];

    int N = in_sizes[0] / 64;
    int E = in_sizes[3];
    int NBUCK = (N + 255) >> BUCK_SHIFT;                 // 256-node buckets
    int C = ((2 * ((E + NBUCK - 1) / NBUCK)) + 255) & ~255;  // bucket capacity
    int NSORT = (E + EPB - 1) / EPB;                     // sort blocks (<=512)

    char* p = (char*)d_ws;
    auto alloc = [&](size_t bytes) {
        char* r = p;
        p += (bytes + 255) & ~(size_t)255;
        return r;
    };
    float*    Wf       = (float*)alloc(W_TOTAL * 4);
    uint4*    fragW2   = (uint4*)alloc(4 * 64 * 16);
    uint4*    frag1    = (uint4*)alloc(512 * 16);
    uint4*    frag2    = (uint4*)alloc(512 * 16);
    uint4*    fragE    = (uint4*)alloc(768 * 16);
    uint4*    fragN    = (uint4*)alloc(768 * 16);
    uint4*    Abf      = (uint4*)alloc((size_t)N * 64);  // bf16 A rows, 64B
    float*    A2       = (float*)alloc((size_t)N * 32 * 4);
    float*    sumh     = (float*)alloc((size_t)N * 64 * 4);
    int2*     seg      = (int2*)alloc((size_t)N * 8);
    unsigned* blockbuf = (unsigned*)alloc((size_t)NSORT * EPB * 4);
    unsigned* packoff  = (unsigned*)alloc((size_t)512 * 512 * 4);
    int*      ssrc     = (int*)alloc((size_t)NBUCK * C * 4);

    prep_weights<<<32, 256, 0, stream>>>(
        (const float*)d_in[5], (const float*)d_in[6],
        (const float*)d_in[7], (const float*)d_in[8],
        (const float*)d_in[9], (const float*)d_in[10],
        (const float*)d_in[11], (const float*)d_in[12], Wf, fragW2,
        frag1, frag2, fragE, fragN);

    int ngroups = (N + 15) / 16;
    k_pre<<<(ngroups + 3) / 4, 256, 0, stream>>>(
        hbuf, ubuf, posbuf, Wf, fragE, fragN, Abf, A2, N);

    k_sortA<<<NSORT, 512, 0, stream>>>(src, dst, blockbuf, packoff, E);

    k_bucketB2<<<NBUCK, 512, (size_t)C * 4, stream>>>(
        blockbuf, packoff, seg, ssrc, N, C, NSORT);

    const int FBLK = 2048;                    // 8192 waves = full machine
    int npw = (N + FBLK * 4 - 1) / (FBLK * 4);
    fused_edge_gather<<<FBLK, 256, 0, stream>>>(
        seg, ssrc, Abf, posbuf, Wf, fragW2, sumh, N, npw);

    k_node4<<<(ngroups + 3) / 4, 256, 0, stream>>>(
        A2, sumh, Wf, frag1, frag2, (float*)d_out, N, ngroups);
}